// Round 6
// baseline (271.006 us; speedup 1.0000x reference)
//
#include <hip/hip_runtime.h>
#include <hip/hip_bf16.h>
#include <cmath>

// Problem constants (match reference)
constexpr int BB_ = 2;
constexpr int T_  = 1024;
constexpr int E_  = 1024;
constexpr int H_  = 8;
constexpr int HD_ = 128;
constexpr int WS_ = 64;
constexpr float TAU_   = 10.0f;
constexpr float SCALE_ = 0.08838834764831843f;  // 1/sqrt(128)

typedef __attribute__((ext_vector_type(8))) short short8;
typedef __attribute__((ext_vector_type(4))) short shortx4;
typedef __attribute__((ext_vector_type(4))) float floatx4;

// Split fp32 -> bf16 hi + bf16 lo (RNE both). x ~= hi + lo to ~2^-17 rel.
struct BfPair { short hi, lo; };
__device__ inline BfPair f2bf_pair(float x) {
  union { float f; unsigned u; } a; a.f = x;
  unsigned rh = (a.u + 0x7FFFu + ((a.u >> 16) & 1u)) >> 16;
  union { unsigned u; float f; } hf; hf.u = rh << 16;
  union { float f; unsigned u; } b; b.f = x - hf.f;
  unsigned rl = (b.u + 0x7FFFu + ((b.u >> 16) & 1u)) >> 16;
  BfPair r; r.hi = (short)rh; r.lo = (short)rl; return r;
}

__device__ inline float bf2f(short s) {
  union { unsigned u; float f; } x;
  x.u = ((unsigned)(unsigned short)s) << 16;
  return x.f;
}

// ---------------------------------------------------------------------------
// Kernel 1: exact stable argsort via rank counting, grid-parallel.
// ---------------------------------------------------------------------------
constexpr int STB_ = 16;  // t-values per block

__global__ __launch_bounds__(256) void sort_rank_kernel(
    const float* __restrict__ coord, int* __restrict__ sidx,
    float* __restrict__ c_s, int* __restrict__ depot) {
  __shared__ float c[T_];
  const int nb = T_ / STB_;
  const int b = blockIdx.x / nb;
  const int t0 = (blockIdx.x % nb) * STB_;
  const float* cb = coord + (size_t)b * T_;
  for (int i = threadIdx.x; i < T_; i += 256) c[i] = cb[i];
  __syncthreads();
  const int tl = threadIdx.x >> 4;
  const int ch = threadIdx.x & 15;
  const int t = t0 + tl;
  const float ct = c[t];
  int rank = 0;
  const int u0 = ch * (T_ / 16);
  #pragma unroll 8
  for (int i = 0; i < T_ / 16; ++i) {
    const int u = u0 + i;
    const float cu = c[u];
    rank += (cu < ct) || (cu == ct && u < t);
  }
  #pragma unroll
  for (int o = 8; o > 0; o >>= 1) rank += __shfl_xor(rank, o);
  if (ch == 0) {
    sidx[b * T_ + rank] = t;
    c_s[b * T_ + rank] = ct;
    if (t == 0) depot[b] = rank;
  }
}

// ---------------------------------------------------------------------------
// Kernel 2a: gather (h -> h_s) fused with fp32 -> bf16 hi/lo split.
// ---------------------------------------------------------------------------
__global__ __launch_bounds__(256) void convert_gather_h(
    const float* __restrict__ h, const int* __restrict__ sidx,
    short* __restrict__ Ahi, short* __restrict__ Alo) {
  const int gr = blockIdx.x;
  const int srow = (gr & ~(T_ - 1)) + sidx[gr];
  const float4 v = *(const float4*)(h + (size_t)srow * E_ + threadIdx.x * 4);
  shortx4 hv, lv;
  BfPair p0 = f2bf_pair(v.x), p1 = f2bf_pair(v.y);
  BfPair p2 = f2bf_pair(v.z), p3 = f2bf_pair(v.w);
  hv.x = p0.hi; hv.y = p1.hi; hv.z = p2.hi; hv.w = p3.hi;
  lv.x = p0.lo; lv.y = p1.lo; lv.z = p2.lo; lv.w = p3.lo;
  const size_t o = (size_t)gr * E_ + threadIdx.x * 4;
  *(shortx4*)(Ahi + o) = hv;
  *(shortx4*)(Alo + o) = lv;
}

// ---------------------------------------------------------------------------
// Kernel 2b: weight fp32 -> bf16 hi/lo split (4 matrices via grid.z).
// ---------------------------------------------------------------------------
struct WConv {
  const float* src[4];
  short* hi[4];
  short* lo[4];
};

__global__ __launch_bounds__(256) void convert_w_kernel(WConv a) {
  const int z = blockIdx.z;
  const size_t idx = ((size_t)blockIdx.x * 256 + threadIdx.x) * 4;
  const float4 v = *(const float4*)(a.src[z] + idx);
  shortx4 hv, lv;
  BfPair p0 = f2bf_pair(v.x), p1 = f2bf_pair(v.y);
  BfPair p2 = f2bf_pair(v.z), p3 = f2bf_pair(v.w);
  hv.x = p0.hi; hv.y = p1.hi; hv.z = p2.hi; hv.w = p3.hi;
  lv.x = p0.lo; lv.y = p1.lo; lv.z = p2.lo; lv.w = p3.lo;
  *(shortx4*)(a.hi[z] + idx) = hv;
  *(shortx4*)(a.lo[z] + idx) = lv;
}

// ---------------------------------------------------------------------------
// Kernel 3: bf16x3 split-precision MFMA GEMM.
// Output mode per grid.z: split -> bf16 hi/lo pair (feeds attention MFMA),
// else fp32 (V, final out). SCATTER stores row m to (batch + sidx[m]).
// ---------------------------------------------------------------------------
struct GemmArgs {
  const short* Whi[3];
  const short* Wlo[3];
  const float* bias[3];
  float* C[3];
  short* Chi[3];
  short* Clo[3];
  int split[3];
};

constexpr int LP_ = 56;  // padded LDS row stride (shorts)

template <int BM, int WM, int SCATTER>
__global__ __launch_bounds__(256, 2) void gemm_bf16x3(
    GemmArgs args, const short* __restrict__ Ahi, const short* __restrict__ Alo,
    const int* __restrict__ sidx) {
  constexpr int TMI = WM / 16;
  const short* __restrict__ Whi = args.Whi[blockIdx.z];
  const short* __restrict__ Wlo = args.Wlo[blockIdx.z];
  const float* __restrict__ bias = args.bias[blockIdx.z];

  __shared__ short As_hi[BM][LP_], As_lo[BM][LP_];
  __shared__ short Bs_hi[128][LP_], Bs_lo[128][LP_];

  const int tid = threadIdx.x;
  const int wv = tid >> 6, lane = tid & 63;
  const int kq = lane >> 4, ln15 = lane & 15;
  const int wm0 = (wv >> 1) * WM, wn0 = (wv & 1) * 64;
  const int m0 = blockIdx.y * BM, n0 = blockIdx.x * 128;

  floatx4 acc[TMI][4];
  #pragma unroll
  for (int i = 0; i < TMI; ++i)
    #pragma unroll
    for (int j = 0; j < 4; ++j) acc[i][j] = (floatx4){0.f, 0.f, 0.f, 0.f};

  for (int k0 = 0; k0 < E_; k0 += 32) {
    #pragma unroll
    for (int i = 0; i < BM * 4 / 256; ++i) {
      const int idx = tid + 256 * i;
      const int r = idx >> 2, c = idx & 3;
      const size_t g = (size_t)(m0 + r) * E_ + k0 + c * 8;
      *(short8*)&As_hi[r][c * 8] = *(const short8*)(Ahi + g);
      *(short8*)&As_lo[r][c * 8] = *(const short8*)(Alo + g);
    }
    #pragma unroll
    for (int i = 0; i < 2; ++i) {
      const int idx = tid + 256 * i;
      const int r = idx >> 2, c = idx & 3;
      const size_t g = (size_t)(n0 + r) * E_ + k0 + c * 8;
      *(short8*)&Bs_hi[r][c * 8] = *(const short8*)(Whi + g);
      *(short8*)&Bs_lo[r][c * 8] = *(const short8*)(Wlo + g);
    }
    __syncthreads();

    short8 ah[TMI], al[TMI], bh[4], bl[4];
    #pragma unroll
    for (int mi = 0; mi < TMI; ++mi) {
      ah[mi] = *(const short8*)&As_hi[wm0 + mi * 16 + ln15][kq * 8];
      al[mi] = *(const short8*)&As_lo[wm0 + mi * 16 + ln15][kq * 8];
    }
    #pragma unroll
    for (int ni = 0; ni < 4; ++ni) {
      bh[ni] = *(const short8*)&Bs_hi[wn0 + ni * 16 + ln15][kq * 8];
      bl[ni] = *(const short8*)&Bs_lo[wn0 + ni * 16 + ln15][kq * 8];
    }
    #pragma unroll
    for (int mi = 0; mi < TMI; ++mi)
      #pragma unroll
      for (int ni = 0; ni < 4; ++ni) {
        acc[mi][ni] = __builtin_amdgcn_mfma_f32_16x16x32_bf16(
            ah[mi], bh[ni], acc[mi][ni], 0, 0, 0);
        acc[mi][ni] = __builtin_amdgcn_mfma_f32_16x16x32_bf16(
            ah[mi], bl[ni], acc[mi][ni], 0, 0, 0);
        acc[mi][ni] = __builtin_amdgcn_mfma_f32_16x16x32_bf16(
            al[mi], bh[ni], acc[mi][ni], 0, 0, 0);
      }
    __syncthreads();
  }

  const int doSplit = args.split[blockIdx.z];
  float* __restrict__ C = args.C[blockIdx.z];
  short* __restrict__ Chi = args.Chi[blockIdx.z];
  short* __restrict__ Clo = args.Clo[blockIdx.z];
  #pragma unroll
  for (int ni = 0; ni < 4; ++ni) {
    const int col = n0 + wn0 + ni * 16 + ln15;
    const float bv = bias[col];
    #pragma unroll
    for (int mi = 0; mi < TMI; ++mi) {
      #pragma unroll
      for (int r = 0; r < 4; ++r) {
        const int m = m0 + wm0 + mi * 16 + kq * 4 + r;
        const int orow = SCATTER ? ((m & ~(T_ - 1)) + sidx[m]) : m;
        const float val = acc[mi][ni][r] + bv;
        if (doSplit) {
          BfPair pr = f2bf_pair(val);
          Chi[(size_t)orow * E_ + col] = pr.hi;
          Clo[(size_t)orow * E_ + col] = pr.lo;
        } else {
          C[(size_t)orow * E_ + col] = val;
        }
      }
    }
  }
}

// ---------------------------------------------------------------------------
// Kernel 4: local sliding-window attention — MFMA QK^T.
// Block = 32 queries, 4 waves. Key slots 0..95 cover [smin, smin+96); col 96
// is the forced depot column. Scores S = (Qhi+Qlo)(Khi+Klo)^T via 3-term
// bf16 MFMA with fragments loaded directly from global (no K/Q LDS staging —
// the R5 kernel's 55.8 KB LDS and 66K ds_read/block are gone). Softmax adds
// SCALE and -dist^2/TAU, masks per-query windows by index. PV stays fp32
// vector with coalesced V reads.
// ---------------------------------------------------------------------------
constexpr int QTm_ = 32;

__global__ __launch_bounds__(256) void attn_local_kernel(
    const short* __restrict__ Qhi, const short* __restrict__ Qlo,
    const short* __restrict__ Khi, const short* __restrict__ Klo,
    const float* __restrict__ V, const float* __restrict__ c_s,
    const int* __restrict__ depot, short* __restrict__ CTXhi,
    short* __restrict__ CTXlo) {
  __shared__ float sc[QTm_][100];   // [query][key slot]; col 96 = depot
  __shared__ float cw[96];
  __shared__ float cq[QTm_];
  __shared__ float kdep[HD_];

  const int tid = threadIdx.x;
  const int ntq = T_ / QTm_;                 // 32
  const int tq = blockIdx.x % ntq;
  const int bh = blockIdx.x / ntq;
  const int h = bh % H_, b = bh / H_;
  const int t0 = tq * QTm_;
  const int dep = depot[b];
  const int smin = min(max(t0 - 32, 0), T_ - 64);
  const size_t baseBH = ((size_t)b * T_) * E_ + (size_t)h * HD_;

  if (tid < 96) {
    cw[tid] = c_s[b * T_ + min(smin + tid, T_ - 1)];
  } else if (tid < 128) {
    cq[tid - 96] = c_s[b * T_ + t0 + tid - 96];
  } else {
    const int d = tid - 128;
    const size_t ko = baseBH + (size_t)dep * E_ + d;
    kdep[d] = bf2f(Khi[ko]) + bf2f(Klo[ko]);
  }
  __syncthreads();

  const int wv = tid >> 6, lane = tid & 63;
  const int ln15 = lane & 15, kq = lane >> 4;

  // ---- MFMA scores: wave (qt = wv>>1) x (key tiles ktb..ktb+2) ----
  {
    const int qt = wv >> 1;
    const int ktb = (wv & 1) * 3;
    const size_t qoff = baseBH + (size_t)(t0 + qt * 16 + ln15) * E_ + kq * 8;
    short8 aH[4], aL[4];
    #pragma unroll
    for (int ks = 0; ks < 4; ++ks) {
      aH[ks] = *(const short8*)(Qhi + qoff + ks * 32);
      aL[ks] = *(const short8*)(Qlo + qoff + ks * 32);
    }
    #pragma unroll
    for (int kt = 0; kt < 3; ++kt) {
      const int key = min(smin + (ktb + kt) * 16 + ln15, T_ - 1);
      const size_t koff = baseBH + (size_t)key * E_ + kq * 8;
      floatx4 acc = (floatx4){0.f, 0.f, 0.f, 0.f};
      #pragma unroll
      for (int ks = 0; ks < 4; ++ks) {
        const short8 bh8 = *(const short8*)(Khi + koff + ks * 32);
        const short8 bl8 = *(const short8*)(Klo + koff + ks * 32);
        acc = __builtin_amdgcn_mfma_f32_16x16x32_bf16(aH[ks], bh8, acc, 0, 0, 0);
        acc = __builtin_amdgcn_mfma_f32_16x16x32_bf16(aH[ks], bl8, acc, 0, 0, 0);
        acc = __builtin_amdgcn_mfma_f32_16x16x32_bf16(aL[ks], bh8, acc, 0, 0, 0);
      }
      #pragma unroll
      for (int r = 0; r < 4; ++r)
        sc[qt * 16 + kq * 4 + r][(ktb + kt) * 16 + ln15] = acc[r];
    }
  }

  // ---- depot column scores (vector dot, wave handles 8 queries) ----
  const float cdep = c_s[b * T_ + dep];
  #pragma unroll
  for (int qi = 0; qi < 8; ++qi) {
    const int q = wv * 8 + qi;
    const int t = t0 + q;
    const size_t qo2 = baseBH + (size_t)t * E_;
    const float q1 = bf2f(Qhi[qo2 + lane]) + bf2f(Qlo[qo2 + lane]);
    const float q2 = bf2f(Qhi[qo2 + 64 + lane]) + bf2f(Qlo[qo2 + 64 + lane]);
    float part = fmaf(q1, kdep[lane], q2 * kdep[lane + 64]);
    #pragma unroll
    for (int o = 32; o > 0; o >>= 1) part += __shfl_xor(part, o);
    if (lane == 0) {
      const int st = min(max(t - 32, 0), T_ - 64);
      const bool masked = (unsigned)(dep - st) < (unsigned)WS_;
      const float dd = cdep - cq[q];
      sc[q][96] = masked ? -3.0e38f
                         : part * SCALE_ - dd * dd * (1.0f / TAU_);
    }
  }
  __syncthreads();

  // ---- softmax (wave handles 8 queries; lane covers slots j and j+64) ----
  #pragma unroll
  for (int qi = 0; qi < 8; ++qi) {
    const int q = wv * 8 + qi;
    const int t = t0 + q;
    const int st = min(max(t - 32, 0), T_ - 64);
    const int base = st - smin;
    const float cqv = cq[q];
    const int j1 = lane;
    float s1 = -3.0e38f;
    if (j1 >= base && j1 < base + 64) {
      const float dd = cw[j1] - cqv;
      s1 = sc[q][j1] * SCALE_ - dd * dd * (1.0f / TAU_);
    }
    const int j2 = 64 + lane;
    float s2 = -3.0e38f;
    if (lane < 32 && j2 >= base && j2 < base + 64) {
      const float dd = cw[j2] - cqv;
      s2 = sc[q][j2] * SCALE_ - dd * dd * (1.0f / TAU_);
    }
    const float sdep = sc[q][96];
    float m = fmaxf(s1, s2);
    #pragma unroll
    for (int o = 32; o > 0; o >>= 1) m = fmaxf(m, __shfl_xor(m, o));
    m = fmaxf(m, sdep);
    const float e1 = expf(s1 - m);
    const float e2 = expf(s2 - m);
    float sum = e1 + e2;
    #pragma unroll
    for (int o = 32; o > 0; o >>= 1) sum += __shfl_xor(sum, o);
    const float edep = expf(sdep - m);
    sum += edep;
    const float inv = 1.0f / sum;
    sc[q][j1] = e1 * inv;
    if (lane < 32) sc[q][j2] = e2 * inv;
    if (lane == 0) sc[q][96] = edep * inv;
  }
  __syncthreads();

  // ---- PV: fp32 vector, coalesced V reads ----
  for (int p = tid; p < QTm_ * HD_; p += 256) {
    const int q = p >> 7, d = p & 127;
    const int t = t0 + q;
    const int st = min(max(t - 32, 0), T_ - 64);
    const int base = st - smin;
    const float* vbase = V + baseBH + d;
    float acc = 0.f;
    #pragma unroll 8
    for (int j = 0; j < WS_; ++j) {
      acc = fmaf(sc[q][base + j], vbase[(size_t)(st + j) * E_], acc);
    }
    acc = fmaf(sc[q][96], vbase[(size_t)dep * E_], acc);
    BfPair pr = f2bf_pair(acc);
    CTXhi[baseBH + (size_t)t * E_ + d] = pr.hi;
    CTXlo[baseBH + (size_t)t * E_ + d] = pr.lo;
  }
}

// ---------------------------------------------------------------------------
// Depot attention, grid-parallel (Q/K now bf16 hi/lo; V fp32).
// ---------------------------------------------------------------------------
constexpr int DCH_ = 16;
constexpr int VSP_ = 8;

__global__ __launch_bounds__(256) void depot_scores_kernel(
    const short* __restrict__ Qhi, const short* __restrict__ Qlo,
    const short* __restrict__ Khi, const short* __restrict__ Klo,
    const float* __restrict__ c_s, const int* __restrict__ depot,
    float* __restrict__ scg) {
  const int chunk = blockIdx.x % DCH_;
  const int bh = blockIdx.x / DCH_;
  const int h = bh % H_, b = bh / H_;
  const int tid = threadIdx.x, wv = tid >> 6, lane = tid & 63;
  const int dep = depot[b];
  const size_t baseBH = ((size_t)b * T_) * E_ + (size_t)h * HD_;
  __shared__ float qd[HD_];
  if (tid < HD_) {
    const size_t qo = baseBH + (size_t)dep * E_ + tid;
    qd[tid] = bf2f(Qhi[qo]) + bf2f(Qlo[qo]);
  }
  __syncthreads();
  const float cdep = c_s[b * T_ + dep];
  constexpr int KPB = T_ / DCH_;
  const int k0 = chunk * KPB + wv * (KPB / 4);
  #pragma unroll 4
  for (int i = 0; i < KPB / 4; ++i) {
    const int k = k0 + i;
    const size_t ko = baseBH + (size_t)k * E_;
    const float k1 = bf2f(Khi[ko + lane]) + bf2f(Klo[ko + lane]);
    const float k2 = bf2f(Khi[ko + 64 + lane]) + bf2f(Klo[ko + 64 + lane]);
    float part = fmaf(qd[lane], k1, qd[lane + 64] * k2);
    #pragma unroll
    for (int o = 32; o > 0; o >>= 1) part += __shfl_xor(part, o);
    if (lane == 0) {
      const float dd = c_s[b * T_ + k] - cdep;
      scg[bh * T_ + k] = part * SCALE_ - dd * dd * (1.0f / TAU_);
    }
  }
}

__global__ __launch_bounds__(256) void depot_softmax_kernel(
    float* __restrict__ scg) {
  __shared__ float sc[T_];
  __shared__ float red[4];
  const int bh = blockIdx.x;
  const int tid = threadIdx.x, wv = tid >> 6, lane = tid & 63;
  float* s = scg + bh * T_;
  float lm = -3.0e38f;
  for (int k = tid; k < T_; k += 256) { sc[k] = s[k]; lm = fmaxf(lm, sc[k]); }
  #pragma unroll
  for (int o = 32; o > 0; o >>= 1) lm = fmaxf(lm, __shfl_xor(lm, o));
  if (lane == 0) red[wv] = lm;
  __syncthreads();
  const float M = fmaxf(fmaxf(red[0], red[1]), fmaxf(red[2], red[3]));
  __syncthreads();
  float ls = 0.f;
  float ev[T_ / 256];
  #pragma unroll
  for (int i = 0; i < T_ / 256; ++i) {
    ev[i] = expf(sc[tid + 256 * i] - M);
    ls += ev[i];
  }
  #pragma unroll
  for (int o = 32; o > 0; o >>= 1) ls += __shfl_xor(ls, o);
  if (lane == 0) red[wv] = ls;
  __syncthreads();
  const float inv = 1.0f / (red[0] + red[1] + red[2] + red[3]);
  #pragma unroll
  for (int i = 0; i < T_ / 256; ++i) s[tid + 256 * i] = ev[i] * inv;
}

__global__ __launch_bounds__(256) void depot_ctx_kernel(
    const float* __restrict__ V, const float* __restrict__ scg,
    float* __restrict__ part) {
  __shared__ float par[2][HD_];
  const int sp = blockIdx.x % VSP_;
  const int bh = blockIdx.x / VSP_;
  const int h = bh % H_, b = bh / H_;
  const int tid = threadIdx.x;
  const int d = tid & 127, kg = tid >> 7;
  const size_t baseBH = ((size_t)b * T_) * E_ + (size_t)h * HD_;
  constexpr int KPB = T_ / VSP_;
  const int k0 = sp * KPB + kg * (KPB / 2);
  const float* vbase = V + baseBH + d;
  const float* a = scg + bh * T_;
  float acc = 0.f;
  #pragma unroll 8
  for (int k = k0; k < k0 + KPB / 2; ++k) {
    acc = fmaf(a[k], vbase[(size_t)k * E_], acc);
  }
  par[kg][d] = acc;
  __syncthreads();
  if (tid < HD_) part[((size_t)sp * BB_ * H_ + bh) * HD_ + tid] =
      par[0][tid] + par[1][tid];
}

__global__ __launch_bounds__(256) void depot_write_kernel(
    const float* __restrict__ part, const int* __restrict__ depot,
    short* __restrict__ CTXhi, short* __restrict__ CTXlo) {
  for (int o = threadIdx.x; o < BB_ * H_ * HD_; o += 256) {
    const int bh = o >> 7, d = o & 127;
    float s = 0.f;
    #pragma unroll
    for (int sp = 0; sp < VSP_; ++sp)
      s += part[((size_t)sp * BB_ * H_ + bh) * HD_ + d];
    const int h = bh % H_, b = bh / H_;
    const int dep = depot[b];
    BfPair pr = f2bf_pair(s);
    const size_t idx = ((size_t)b * T_ + dep) * E_ + (size_t)h * HD_ + d;
    CTXhi[idx] = pr.hi;
    CTXlo[idx] = pr.lo;
  }
}

// ---------------------------------------------------------------------------
extern "C" void kernel_launch(void* const* d_in, const int* in_sizes, int n_in,
                              void* d_out, int out_size, void* d_ws, size_t ws_size,
                              hipStream_t stream) {
  const float* h     = (const float*)d_in[0];
  const float* coord = (const float*)d_in[1];
  const float* Wq    = (const float*)d_in[2];
  const float* Wqb   = (const float*)d_in[3];
  const float* Wk    = (const float*)d_in[4];
  const float* Wkb   = (const float*)d_in[5];
  const float* Wv    = (const float*)d_in[6];
  const float* Wvb   = (const float*)d_in[7];
  const float* Wo    = (const float*)d_in[8];
  const float* Wob   = (const float*)d_in[9];
  float* out = (float*)d_out;

  char* ws = (char*)d_ws;
  const size_t MATF = (size_t)BB_ * T_ * E_ * 4;  // 8 MB fp32
  const size_t MATB = (size_t)BB_ * T_ * E_ * 2;  // 4 MB bf16
  const size_t WB   = (size_t)E_ * E_ * 2;        // 2 MB bf16
  size_t off = 0;
  short* Qhi = (short*)(ws + off); off += MATB;
  short* Qlo = (short*)(ws + off); off += MATB;
  short* Khi = (short*)(ws + off); off += MATB;
  short* Klo = (short*)(ws + off); off += MATB;
  float* Vb  = (float*)(ws + off); off += MATF;
  short* Ahi = (short*)(ws + off); off += MATB;
  short* Alo = (short*)(ws + off); off += MATB;
  short* CThi = (short*)(ws + off); off += MATB;
  short* CTlo = (short*)(ws + off); off += MATB;
  short* Whi[4], *Wlo[4];
  for (int i = 0; i < 4; ++i) { Whi[i] = (short*)(ws + off); off += WB; }
  for (int i = 0; i < 4; ++i) { Wlo[i] = (short*)(ws + off); off += WB; }
  float* c_s = (float*)(ws + off); off += (size_t)BB_ * T_ * 4;
  int* sidx  = (int*)(ws + off);   off += (size_t)BB_ * T_ * 4;
  int* depo  = (int*)(ws + off);   off += 256;
  float* scg  = (float*)(ws + off); off += (size_t)BB_ * H_ * T_ * 4;
  float* dpar = (float*)(ws + off); off += (size_t)VSP_ * BB_ * H_ * HD_ * 4;

  // 1. stable sort by coordinate (grid-parallel rank counting)
  sort_rank_kernel<<<BB_ * (T_ / STB_), 256, 0, stream>>>(coord, sidx, c_s, depo);

  // 2a. gather + split h
  convert_gather_h<<<BB_ * T_, 256, 0, stream>>>(h, sidx, Ahi, Alo);

  // 2b. split weights
  WConv wc;
  wc.src[0] = Wq; wc.src[1] = Wk; wc.src[2] = Wv; wc.src[3] = Wo;
  for (int i = 0; i < 4; ++i) { wc.hi[i] = Whi[i]; wc.lo[i] = Wlo[i]; }
  convert_w_kernel<<<dim3(E_ * E_ / 1024, 1, 4), 256, 0, stream>>>(wc);

  // 3. QKV projections: Q,K -> bf16 hi/lo; V -> fp32
  GemmArgs qa;
  qa.Whi[0] = Whi[0]; qa.Whi[1] = Whi[1]; qa.Whi[2] = Whi[2];
  qa.Wlo[0] = Wlo[0]; qa.Wlo[1] = Wlo[1]; qa.Wlo[2] = Wlo[2];
  qa.bias[0] = Wqb; qa.bias[1] = Wkb; qa.bias[2] = Wvb;
  qa.C[0] = nullptr; qa.C[1] = nullptr; qa.C[2] = Vb;
  qa.Chi[0] = Qhi; qa.Clo[0] = Qlo;
  qa.Chi[1] = Khi; qa.Clo[1] = Klo;
  qa.Chi[2] = nullptr; qa.Clo[2] = nullptr;
  qa.split[0] = 1; qa.split[1] = 1; qa.split[2] = 0;
  gemm_bf16x3<128, 64, 0><<<dim3(E_ / 128, (BB_ * T_) / 128, 3), 256, 0, stream>>>(
      qa, Ahi, Alo, sidx);

  // 4. sliding-window attention (MFMA QK^T) -> ctx (bf16-split)
  attn_local_kernel<<<BB_ * H_ * (T_ / QTm_), 256, 0, stream>>>(
      Qhi, Qlo, Khi, Klo, Vb, c_s, depo, CThi, CTlo);

  // 5. depot full attention, grid-parallel (overwrites ctx depot rows)
  depot_scores_kernel<<<BB_ * H_ * DCH_, 256, 0, stream>>>(
      Qhi, Qlo, Khi, Klo, c_s, depo, scg);
  depot_softmax_kernel<<<BB_ * H_, 256, 0, stream>>>(scg);
  depot_ctx_kernel<<<BB_ * H_ * VSP_, 256, 0, stream>>>(Vb, scg, dpar);
  depot_write_kernel<<<1, 256, 0, stream>>>(dpar, depo, CThi, CTlo);

  // 6. output projection with fused un-sort scatter
  GemmArgs oa;
  oa.Whi[0] = Whi[3]; oa.Whi[1] = Whi[3]; oa.Whi[2] = Whi[3];
  oa.Wlo[0] = Wlo[3]; oa.Wlo[1] = Wlo[3]; oa.Wlo[2] = Wlo[3];
  oa.bias[0] = Wob; oa.bias[1] = Wob; oa.bias[2] = Wob;
  oa.C[0] = out; oa.C[1] = out; oa.C[2] = out;
  oa.Chi[0] = oa.Chi[1] = oa.Chi[2] = nullptr;
  oa.Clo[0] = oa.Clo[1] = oa.Clo[2] = nullptr;
  oa.split[0] = oa.split[1] = oa.split[2] = 0;
  gemm_bf16x3<64, 32, 1><<<dim3(E_ / 128, (BB_ * T_) / 64, 1), 256, 0, stream>>>(
      oa, CThi, CTlo, sidx);
}

// Round 7
// 232.965 us; speedup vs baseline: 1.1633x; 1.1633x over previous
//
#include <hip/hip_runtime.h>
#include <hip/hip_bf16.h>
#include <cmath>

// Problem constants (match reference)
constexpr int BB_ = 2;
constexpr int T_  = 1024;
constexpr int E_  = 1024;
constexpr int H_  = 8;
constexpr int HD_ = 128;
constexpr int WS_ = 64;
constexpr float TAU_   = 10.0f;
constexpr float SCALE_ = 0.08838834764831843f;  // 1/sqrt(128)

typedef __attribute__((ext_vector_type(8))) short short8;
typedef __attribute__((ext_vector_type(4))) short shortx4;
typedef __attribute__((ext_vector_type(4))) float floatx4;

// Split fp32 -> bf16 hi + bf16 lo (RNE both). x ~= hi + lo to ~2^-17 rel.
struct BfPair { short hi, lo; };
__device__ inline BfPair f2bf_pair(float x) {
  union { float f; unsigned u; } a; a.f = x;
  unsigned rh = (a.u + 0x7FFFu + ((a.u >> 16) & 1u)) >> 16;
  union { unsigned u; float f; } hf; hf.u = rh << 16;
  union { float f; unsigned u; } b; b.f = x - hf.f;
  unsigned rl = (b.u + 0x7FFFu + ((b.u >> 16) & 1u)) >> 16;
  BfPair r; r.hi = (short)rh; r.lo = (short)rl; return r;
}

__device__ inline float bf2f(short s) {
  union { unsigned u; float f; } x;
  x.u = ((unsigned)(unsigned short)s) << 16;
  return x.f;
}

// ---------------------------------------------------------------------------
// Kernel 1: exact stable argsort via rank counting, grid-parallel.
// ---------------------------------------------------------------------------
constexpr int STB_ = 16;  // t-values per block

__global__ __launch_bounds__(256) void sort_rank_kernel(
    const float* __restrict__ coord, int* __restrict__ sidx,
    float* __restrict__ c_s, int* __restrict__ depot) {
  __shared__ float c[T_];
  const int nb = T_ / STB_;
  const int b = blockIdx.x / nb;
  const int t0 = (blockIdx.x % nb) * STB_;
  const float* cb = coord + (size_t)b * T_;
  for (int i = threadIdx.x; i < T_; i += 256) c[i] = cb[i];
  __syncthreads();
  const int tl = threadIdx.x >> 4;
  const int ch = threadIdx.x & 15;
  const int t = t0 + tl;
  const float ct = c[t];
  int rank = 0;
  const int u0 = ch * (T_ / 16);
  #pragma unroll 8
  for (int i = 0; i < T_ / 16; ++i) {
    const int u = u0 + i;
    const float cu = c[u];
    rank += (cu < ct) || (cu == ct && u < t);
  }
  #pragma unroll
  for (int o = 8; o > 0; o >>= 1) rank += __shfl_xor(rank, o);
  if (ch == 0) {
    sidx[b * T_ + rank] = t;
    c_s[b * T_ + rank] = ct;
    if (t == 0) depot[b] = rank;
  }
}

// ---------------------------------------------------------------------------
// Kernel 2a: gather (h -> h_s) fused with fp32 -> bf16 hi/lo split.
// ---------------------------------------------------------------------------
__global__ __launch_bounds__(256) void convert_gather_h(
    const float* __restrict__ h, const int* __restrict__ sidx,
    short* __restrict__ Ahi, short* __restrict__ Alo) {
  const int gr = blockIdx.x;
  const int srow = (gr & ~(T_ - 1)) + sidx[gr];
  const float4 v = *(const float4*)(h + (size_t)srow * E_ + threadIdx.x * 4);
  shortx4 hv, lv;
  BfPair p0 = f2bf_pair(v.x), p1 = f2bf_pair(v.y);
  BfPair p2 = f2bf_pair(v.z), p3 = f2bf_pair(v.w);
  hv.x = p0.hi; hv.y = p1.hi; hv.z = p2.hi; hv.w = p3.hi;
  lv.x = p0.lo; lv.y = p1.lo; lv.z = p2.lo; lv.w = p3.lo;
  const size_t o = (size_t)gr * E_ + threadIdx.x * 4;
  *(shortx4*)(Ahi + o) = hv;
  *(shortx4*)(Alo + o) = lv;
}

// ---------------------------------------------------------------------------
// Kernel 2b: weight fp32 -> bf16 hi/lo split (4 matrices via grid.z).
// ---------------------------------------------------------------------------
struct WConv {
  const float* src[4];
  short* hi[4];
  short* lo[4];
};

__global__ __launch_bounds__(256) void convert_w_kernel(WConv a) {
  const int z = blockIdx.z;
  const size_t idx = ((size_t)blockIdx.x * 256 + threadIdx.x) * 4;
  const float4 v = *(const float4*)(a.src[z] + idx);
  shortx4 hv, lv;
  BfPair p0 = f2bf_pair(v.x), p1 = f2bf_pair(v.y);
  BfPair p2 = f2bf_pair(v.z), p3 = f2bf_pair(v.w);
  hv.x = p0.hi; hv.y = p1.hi; hv.z = p2.hi; hv.w = p3.hi;
  lv.x = p0.lo; lv.y = p1.lo; lv.z = p2.lo; lv.w = p3.lo;
  *(shortx4*)(a.hi[z] + idx) = hv;
  *(shortx4*)(a.lo[z] + idx) = lv;
}

// ---------------------------------------------------------------------------
// Kernel 3: bf16x3 split-precision MFMA GEMM.  (unchanged — passed)
// ---------------------------------------------------------------------------
struct GemmArgs {
  const short* Whi[3];
  const short* Wlo[3];
  const float* bias[3];
  float* C[3];
  short* Chi[3];
  short* Clo[3];
  int split[3];
};

constexpr int LP_ = 56;  // padded LDS row stride (shorts)

template <int BM, int WM, int SCATTER>
__global__ __launch_bounds__(256, 2) void gemm_bf16x3(
    GemmArgs args, const short* __restrict__ Ahi, const short* __restrict__ Alo,
    const int* __restrict__ sidx) {
  constexpr int TMI = WM / 16;
  const short* __restrict__ Whi = args.Whi[blockIdx.z];
  const short* __restrict__ Wlo = args.Wlo[blockIdx.z];
  const float* __restrict__ bias = args.bias[blockIdx.z];

  __shared__ short As_hi[BM][LP_], As_lo[BM][LP_];
  __shared__ short Bs_hi[128][LP_], Bs_lo[128][LP_];

  const int tid = threadIdx.x;
  const int wv = tid >> 6, lane = tid & 63;
  const int kq = lane >> 4, ln15 = lane & 15;
  const int wm0 = (wv >> 1) * WM, wn0 = (wv & 1) * 64;
  const int m0 = blockIdx.y * BM, n0 = blockIdx.x * 128;

  floatx4 acc[TMI][4];
  #pragma unroll
  for (int i = 0; i < TMI; ++i)
    #pragma unroll
    for (int j = 0; j < 4; ++j) acc[i][j] = (floatx4){0.f, 0.f, 0.f, 0.f};

  for (int k0 = 0; k0 < E_; k0 += 32) {
    #pragma unroll
    for (int i = 0; i < BM * 4 / 256; ++i) {
      const int idx = tid + 256 * i;
      const int r = idx >> 2, c = idx & 3;
      const size_t g = (size_t)(m0 + r) * E_ + k0 + c * 8;
      *(short8*)&As_hi[r][c * 8] = *(const short8*)(Ahi + g);
      *(short8*)&As_lo[r][c * 8] = *(const short8*)(Alo + g);
    }
    #pragma unroll
    for (int i = 0; i < 2; ++i) {
      const int idx = tid + 256 * i;
      const int r = idx >> 2, c = idx & 3;
      const size_t g = (size_t)(n0 + r) * E_ + k0 + c * 8;
      *(short8*)&Bs_hi[r][c * 8] = *(const short8*)(Whi + g);
      *(short8*)&Bs_lo[r][c * 8] = *(const short8*)(Wlo + g);
    }
    __syncthreads();

    short8 ah[TMI], al[TMI], bh[4], bl[4];
    #pragma unroll
    for (int mi = 0; mi < TMI; ++mi) {
      ah[mi] = *(const short8*)&As_hi[wm0 + mi * 16 + ln15][kq * 8];
      al[mi] = *(const short8*)&As_lo[wm0 + mi * 16 + ln15][kq * 8];
    }
    #pragma unroll
    for (int ni = 0; ni < 4; ++ni) {
      bh[ni] = *(const short8*)&Bs_hi[wn0 + ni * 16 + ln15][kq * 8];
      bl[ni] = *(const short8*)&Bs_lo[wn0 + ni * 16 + ln15][kq * 8];
    }
    #pragma unroll
    for (int mi = 0; mi < TMI; ++mi)
      #pragma unroll
      for (int ni = 0; ni < 4; ++ni) {
        acc[mi][ni] = __builtin_amdgcn_mfma_f32_16x16x32_bf16(
            ah[mi], bh[ni], acc[mi][ni], 0, 0, 0);
        acc[mi][ni] = __builtin_amdgcn_mfma_f32_16x16x32_bf16(
            ah[mi], bl[ni], acc[mi][ni], 0, 0, 0);
        acc[mi][ni] = __builtin_amdgcn_mfma_f32_16x16x32_bf16(
            al[mi], bh[ni], acc[mi][ni], 0, 0, 0);
      }
    __syncthreads();
  }

  const int doSplit = args.split[blockIdx.z];
  float* __restrict__ C = args.C[blockIdx.z];
  short* __restrict__ Chi = args.Chi[blockIdx.z];
  short* __restrict__ Clo = args.Clo[blockIdx.z];
  #pragma unroll
  for (int ni = 0; ni < 4; ++ni) {
    const int col = n0 + wn0 + ni * 16 + ln15;
    const float bv = bias[col];
    #pragma unroll
    for (int mi = 0; mi < TMI; ++mi) {
      #pragma unroll
      for (int r = 0; r < 4; ++r) {
        const int m = m0 + wm0 + mi * 16 + kq * 4 + r;
        const int orow = SCATTER ? ((m & ~(T_ - 1)) + sidx[m]) : m;
        const float val = acc[mi][ni][r] + bv;
        if (doSplit) {
          BfPair pr = f2bf_pair(val);
          Chi[(size_t)orow * E_ + col] = pr.hi;
          Clo[(size_t)orow * E_ + col] = pr.lo;
        } else {
          C[(size_t)orow * E_ + col] = val;
        }
      }
    }
  }
}

// ---------------------------------------------------------------------------
// Kernel 4: local sliding-window attention — MFMA QK^T + slot-unified PV.
// QTm=16 queries/block -> grid 1024 (4 blocks/CU, was grid-limited at 2).
// Key slots 0..79 cover [smin, smin+80) (5 MFMA key tiles); slot 80 = forced
// depot column. Softmax writes normalized weights for ALL slots (0 outside
// each query's 64-key window), so PV needs no per-q window logic: one pass
// over 81 slots, V loaded once per (slot, dim-lane) and weights broadcast
// from LDS. Per-lane V loads: 162 (was 1040).
// ---------------------------------------------------------------------------
constexpr int QTm_ = 16;
constexpr int NSL_ = 80;   // window key slots; +1 depot slot at index 80

__global__ __launch_bounds__(256) void attn_local_kernel(
    const short* __restrict__ Qhi, const short* __restrict__ Qlo,
    const short* __restrict__ Khi, const short* __restrict__ Klo,
    const float* __restrict__ V, const float* __restrict__ c_s,
    const int* __restrict__ depot, short* __restrict__ CTXhi,
    short* __restrict__ CTXlo) {
  __shared__ float sc[QTm_][88];    // [query][slot]; slot 80 = depot
  __shared__ float cw[NSL_];
  __shared__ float cq[QTm_];
  __shared__ float kdep[HD_];

  const int tid = threadIdx.x;
  const int ntq = T_ / QTm_;                 // 64
  const int tq = blockIdx.x % ntq;
  const int bh = blockIdx.x / ntq;
  const int h = bh % H_, b = bh / H_;
  const int t0 = tq * QTm_;
  const int dep = depot[b];
  const int smin = min(max(t0 - 32, 0), T_ - WS_);
  const size_t baseBH = ((size_t)b * T_) * E_ + (size_t)h * HD_;

  if (tid < NSL_) {
    cw[tid] = c_s[b * T_ + min(smin + tid, T_ - 1)];
  } else if (tid < NSL_ + QTm_) {
    cq[tid - NSL_] = c_s[b * T_ + t0 + tid - NSL_];
  } else if (tid >= 128) {
    const int d = tid - 128;
    const size_t ko = baseBH + (size_t)dep * E_ + d;
    kdep[d] = bf2f(Khi[ko]) + bf2f(Klo[ko]);
  }
  __syncthreads();

  const int wv = tid >> 6, lane = tid & 63;
  const int ln15 = lane & 15, kq = lane >> 4;

  // ---- MFMA scores: all waves share the Q tile; wave w covers key tiles
  //      {w} (+ tile 4 for wave 0) ----
  {
    const size_t qoff = baseBH + (size_t)(t0 + ln15) * E_ + kq * 8;
    short8 aH[4], aL[4];
    #pragma unroll
    for (int ks = 0; ks < 4; ++ks) {
      aH[ks] = *(const short8*)(Qhi + qoff + ks * 32);
      aL[ks] = *(const short8*)(Qlo + qoff + ks * 32);
    }
    for (int kt = wv; kt < 5; kt += 4) {
      const int key = min(smin + kt * 16 + ln15, T_ - 1);
      const size_t koff = baseBH + (size_t)key * E_ + kq * 8;
      floatx4 acc = (floatx4){0.f, 0.f, 0.f, 0.f};
      #pragma unroll
      for (int ks = 0; ks < 4; ++ks) {
        const short8 bh8 = *(const short8*)(Khi + koff + ks * 32);
        const short8 bl8 = *(const short8*)(Klo + koff + ks * 32);
        acc = __builtin_amdgcn_mfma_f32_16x16x32_bf16(aH[ks], bh8, acc, 0, 0, 0);
        acc = __builtin_amdgcn_mfma_f32_16x16x32_bf16(aH[ks], bl8, acc, 0, 0, 0);
        acc = __builtin_amdgcn_mfma_f32_16x16x32_bf16(aL[ks], bh8, acc, 0, 0, 0);
      }
      #pragma unroll
      for (int r = 0; r < 4; ++r)
        sc[kq * 4 + r][kt * 16 + ln15] = acc[r];
    }
  }

  // ---- depot column raw scores (vector dot; wave handles 4 queries) ----
  const float cdep = c_s[b * T_ + dep];
  #pragma unroll
  for (int qi = 0; qi < 4; ++qi) {
    const int q = wv * 4 + qi;
    const int t = t0 + q;
    const size_t qo2 = baseBH + (size_t)t * E_;
    const float q1 = bf2f(Qhi[qo2 + lane]) + bf2f(Qlo[qo2 + lane]);
    const float q2 = bf2f(Qhi[qo2 + 64 + lane]) + bf2f(Qlo[qo2 + 64 + lane]);
    float part = fmaf(q1, kdep[lane], q2 * kdep[lane + 64]);
    #pragma unroll
    for (int o = 32; o > 0; o >>= 1) part += __shfl_xor(part, o);
    if (lane == 0) {
      const int st = min(max(t - 32, 0), T_ - WS_);
      const bool masked = (unsigned)(dep - st) < (unsigned)WS_;
      const float dd = cdep - cq[q];
      sc[q][80] = masked ? -3.0e38f
                         : part * SCALE_ - dd * dd * (1.0f / TAU_);
    }
  }
  __syncthreads();

  // ---- softmax (wave handles 4 queries); invalid slots get weight 0 ----
  #pragma unroll
  for (int qi = 0; qi < 4; ++qi) {
    const int q = wv * 4 + qi;
    const int t = t0 + q;
    const int st = min(max(t - 32, 0), T_ - WS_);
    const int base = st - smin;            // 0..16
    const float cqv = cq[q];
    const int j1 = lane;
    float s1 = -3.0e38f;
    if (j1 >= base && j1 < base + WS_) {
      const float dd = cw[j1] - cqv;
      s1 = sc[q][j1] * SCALE_ - dd * dd * (1.0f / TAU_);
    }
    const int j2 = 64 + lane;
    float s2 = -3.0e38f;
    if (lane < 16 && j2 >= base && j2 < base + WS_) {
      const float dd = cw[j2] - cqv;
      s2 = sc[q][j2] * SCALE_ - dd * dd * (1.0f / TAU_);
    }
    const float sdep = sc[q][80];
    float m = fmaxf(s1, s2);
    #pragma unroll
    for (int o = 32; o > 0; o >>= 1) m = fmaxf(m, __shfl_xor(m, o));
    m = fmaxf(m, sdep);
    const float e1 = expf(s1 - m);
    const float e2 = (lane < 16) ? expf(s2 - m) : 0.f;
    float sum = e1 + e2;
    #pragma unroll
    for (int o = 32; o > 0; o >>= 1) sum += __shfl_xor(sum, o);
    const float edep = expf(sdep - m);
    sum += edep;
    const float inv = 1.0f / sum;
    sc[q][j1] = e1 * inv;
    if (lane < 16) sc[q][j2] = e2 * inv;
    if (lane == 0) sc[q][80] = edep * inv;
  }
  __syncthreads();

  // ---- PV: one pass over 81 slots; V loaded once per (slot, dim-lane) ----
  {
    const int d1 = lane, d2 = lane + 64;
    float acc0[4], acc1[4];
    #pragma unroll
    for (int qi = 0; qi < 4; ++qi) { acc0[qi] = 0.f; acc1[qi] = 0.f; }
    for (int j = 0; j <= NSL_; ++j) {
      const int row = (j < NSL_) ? min(smin + j, T_ - 1) : dep;
      const size_t vo = baseBH + (size_t)row * E_;
      const float v1 = V[vo + d1];
      const float v2 = V[vo + d2];
      #pragma unroll
      for (int qi = 0; qi < 4; ++qi) {
        const float w = sc[wv * 4 + qi][j];
        acc0[qi] = fmaf(w, v1, acc0[qi]);
        acc1[qi] = fmaf(w, v2, acc1[qi]);
      }
    }
    #pragma unroll
    for (int qi = 0; qi < 4; ++qi) {
      const int t = t0 + wv * 4 + qi;
      const size_t co = baseBH + (size_t)t * E_;
      BfPair p1 = f2bf_pair(acc0[qi]);
      BfPair p2 = f2bf_pair(acc1[qi]);
      CTXhi[co + d1] = p1.hi;  CTXlo[co + d1] = p1.lo;
      CTXhi[co + d2] = p2.hi;  CTXlo[co + d2] = p2.lo;
    }
  }
}

// ---------------------------------------------------------------------------
// Depot attention, grid-parallel (unchanged — passed).
// ---------------------------------------------------------------------------
constexpr int DCH_ = 16;
constexpr int VSP_ = 8;

__global__ __launch_bounds__(256) void depot_scores_kernel(
    const short* __restrict__ Qhi, const short* __restrict__ Qlo,
    const short* __restrict__ Khi, const short* __restrict__ Klo,
    const float* __restrict__ c_s, const int* __restrict__ depot,
    float* __restrict__ scg) {
  const int chunk = blockIdx.x % DCH_;
  const int bh = blockIdx.x / DCH_;
  const int h = bh % H_, b = bh / H_;
  const int tid = threadIdx.x, wv = tid >> 6, lane = tid & 63;
  const int dep = depot[b];
  const size_t baseBH = ((size_t)b * T_) * E_ + (size_t)h * HD_;
  __shared__ float qd[HD_];
  if (tid < HD_) {
    const size_t qo = baseBH + (size_t)dep * E_ + tid;
    qd[tid] = bf2f(Qhi[qo]) + bf2f(Qlo[qo]);
  }
  __syncthreads();
  const float cdep = c_s[b * T_ + dep];
  constexpr int KPB = T_ / DCH_;
  const int k0 = chunk * KPB + wv * (KPB / 4);
  #pragma unroll 4
  for (int i = 0; i < KPB / 4; ++i) {
    const int k = k0 + i;
    const size_t ko = baseBH + (size_t)k * E_;
    const float k1 = bf2f(Khi[ko + lane]) + bf2f(Klo[ko + lane]);
    const float k2 = bf2f(Khi[ko + 64 + lane]) + bf2f(Klo[ko + 64 + lane]);
    float part = fmaf(qd[lane], k1, qd[lane + 64] * k2);
    #pragma unroll
    for (int o = 32; o > 0; o >>= 1) part += __shfl_xor(part, o);
    if (lane == 0) {
      const float dd = c_s[b * T_ + k] - cdep;
      scg[bh * T_ + k] = part * SCALE_ - dd * dd * (1.0f / TAU_);
    }
  }
}

__global__ __launch_bounds__(256) void depot_softmax_kernel(
    float* __restrict__ scg) {
  __shared__ float sc[T_];
  __shared__ float red[4];
  const int bh = blockIdx.x;
  const int tid = threadIdx.x, wv = tid >> 6, lane = tid & 63;
  float* s = scg + bh * T_;
  float lm = -3.0e38f;
  for (int k = tid; k < T_; k += 256) { sc[k] = s[k]; lm = fmaxf(lm, sc[k]); }
  #pragma unroll
  for (int o = 32; o > 0; o >>= 1) lm = fmaxf(lm, __shfl_xor(lm, o));
  if (lane == 0) red[wv] = lm;
  __syncthreads();
  const float M = fmaxf(fmaxf(red[0], red[1]), fmaxf(red[2], red[3]));
  __syncthreads();
  float ls = 0.f;
  float ev[T_ / 256];
  #pragma unroll
  for (int i = 0; i < T_ / 256; ++i) {
    ev[i] = expf(sc[tid + 256 * i] - M);
    ls += ev[i];
  }
  #pragma unroll
  for (int o = 32; o > 0; o >>= 1) ls += __shfl_xor(ls, o);
  if (lane == 0) red[wv] = ls;
  __syncthreads();
  const float inv = 1.0f / (red[0] + red[1] + red[2] + red[3]);
  #pragma unroll
  for (int i = 0; i < T_ / 256; ++i) s[tid + 256 * i] = ev[i] * inv;
}

__global__ __launch_bounds__(256) void depot_ctx_kernel(
    const float* __restrict__ V, const float* __restrict__ scg,
    float* __restrict__ part) {
  __shared__ float par[2][HD_];
  const int sp = blockIdx.x % VSP_;
  const int bh = blockIdx.x / VSP_;
  const int h = bh % H_, b = bh / H_;
  const int tid = threadIdx.x;
  const int d = tid & 127, kg = tid >> 7;
  const size_t baseBH = ((size_t)b * T_) * E_ + (size_t)h * HD_;
  constexpr int KPB = T_ / VSP_;
  const int k0 = sp * KPB + kg * (KPB / 2);
  const float* vbase = V + baseBH + d;
  const float* a = scg + bh * T_;
  float acc = 0.f;
  #pragma unroll 8
  for (int k = k0; k < k0 + KPB / 2; ++k) {
    acc = fmaf(a[k], vbase[(size_t)k * E_], acc);
  }
  par[kg][d] = acc;
  __syncthreads();
  if (tid < HD_) part[((size_t)sp * BB_ * H_ + bh) * HD_ + tid] =
      par[0][tid] + par[1][tid];
}

__global__ __launch_bounds__(256) void depot_write_kernel(
    const float* __restrict__ part, const int* __restrict__ depot,
    short* __restrict__ CTXhi, short* __restrict__ CTXlo) {
  for (int o = threadIdx.x; o < BB_ * H_ * HD_; o += 256) {
    const int bh = o >> 7, d = o & 127;
    float s = 0.f;
    #pragma unroll
    for (int sp = 0; sp < VSP_; ++sp)
      s += part[((size_t)sp * BB_ * H_ + bh) * HD_ + d];
    const int h = bh % H_, b = bh / H_;
    const int dep = depot[b];
    BfPair pr = f2bf_pair(s);
    const size_t idx = ((size_t)b * T_ + dep) * E_ + (size_t)h * HD_ + d;
    CTXhi[idx] = pr.hi;
    CTXlo[idx] = pr.lo;
  }
}

// ---------------------------------------------------------------------------
extern "C" void kernel_launch(void* const* d_in, const int* in_sizes, int n_in,
                              void* d_out, int out_size, void* d_ws, size_t ws_size,
                              hipStream_t stream) {
  const float* h     = (const float*)d_in[0];
  const float* coord = (const float*)d_in[1];
  const float* Wq    = (const float*)d_in[2];
  const float* Wqb   = (const float*)d_in[3];
  const float* Wk    = (const float*)d_in[4];
  const float* Wkb   = (const float*)d_in[5];
  const float* Wv    = (const float*)d_in[6];
  const float* Wvb   = (const float*)d_in[7];
  const float* Wo    = (const float*)d_in[8];
  const float* Wob   = (const float*)d_in[9];
  float* out = (float*)d_out;

  char* ws = (char*)d_ws;
  const size_t MATF = (size_t)BB_ * T_ * E_ * 4;  // 8 MB fp32
  const size_t MATB = (size_t)BB_ * T_ * E_ * 2;  // 4 MB bf16
  const size_t WB   = (size_t)E_ * E_ * 2;        // 2 MB bf16
  size_t off = 0;
  short* Qhi = (short*)(ws + off); off += MATB;
  short* Qlo = (short*)(ws + off); off += MATB;
  short* Khi = (short*)(ws + off); off += MATB;
  short* Klo = (short*)(ws + off); off += MATB;
  float* Vb  = (float*)(ws + off); off += MATF;
  short* Ahi = (short*)(ws + off); off += MATB;
  short* Alo = (short*)(ws + off); off += MATB;
  short* CThi = (short*)(ws + off); off += MATB;
  short* CTlo = (short*)(ws + off); off += MATB;
  short* Whi[4], *Wlo[4];
  for (int i = 0; i < 4; ++i) { Whi[i] = (short*)(ws + off); off += WB; }
  for (int i = 0; i < 4; ++i) { Wlo[i] = (short*)(ws + off); off += WB; }
  float* c_s = (float*)(ws + off); off += (size_t)BB_ * T_ * 4;
  int* sidx  = (int*)(ws + off);   off += (size_t)BB_ * T_ * 4;
  int* depo  = (int*)(ws + off);   off += 256;
  float* scg  = (float*)(ws + off); off += (size_t)BB_ * H_ * T_ * 4;
  float* dpar = (float*)(ws + off); off += (size_t)VSP_ * BB_ * H_ * HD_ * 4;

  // 1. stable sort by coordinate (grid-parallel rank counting)
  sort_rank_kernel<<<BB_ * (T_ / STB_), 256, 0, stream>>>(coord, sidx, c_s, depo);

  // 2a. gather + split h
  convert_gather_h<<<BB_ * T_, 256, 0, stream>>>(h, sidx, Ahi, Alo);

  // 2b. split weights
  WConv wc;
  wc.src[0] = Wq; wc.src[1] = Wk; wc.src[2] = Wv; wc.src[3] = Wo;
  for (int i = 0; i < 4; ++i) { wc.hi[i] = Whi[i]; wc.lo[i] = Wlo[i]; }
  convert_w_kernel<<<dim3(E_ * E_ / 1024, 1, 4), 256, 0, stream>>>(wc);

  // 3. QKV projections: Q,K -> bf16 hi/lo; V -> fp32
  GemmArgs qa;
  qa.Whi[0] = Whi[0]; qa.Whi[1] = Whi[1]; qa.Whi[2] = Whi[2];
  qa.Wlo[0] = Wlo[0]; qa.Wlo[1] = Wlo[1]; qa.Wlo[2] = Wlo[2];
  qa.bias[0] = Wqb; qa.bias[1] = Wkb; qa.bias[2] = Wvb;
  qa.C[0] = nullptr; qa.C[1] = nullptr; qa.C[2] = Vb;
  qa.Chi[0] = Qhi; qa.Clo[0] = Qlo;
  qa.Chi[1] = Khi; qa.Clo[1] = Klo;
  qa.Chi[2] = nullptr; qa.Clo[2] = nullptr;
  qa.split[0] = 1; qa.split[1] = 1; qa.split[2] = 0;
  gemm_bf16x3<128, 64, 0><<<dim3(E_ / 128, (BB_ * T_) / 128, 3), 256, 0, stream>>>(
      qa, Ahi, Alo, sidx);

  // 4. sliding-window attention (MFMA QK^T, slot-unified PV)
  attn_local_kernel<<<BB_ * H_ * (T_ / QTm_), 256, 0, stream>>>(
      Qhi, Qlo, Khi, Klo, Vb, c_s, depo, CThi, CTlo);

  // 5. depot full attention, grid-parallel (overwrites ctx depot rows)
  depot_scores_kernel<<<BB_ * H_ * DCH_, 256, 0, stream>>>(
      Qhi, Qlo, Khi, Klo, c_s, depo, scg);
  depot_softmax_kernel<<<BB_ * H_, 256, 0, stream>>>(scg);
  depot_ctx_kernel<<<BB_ * H_ * VSP_, 256, 0, stream>>>(Vb, scg, dpar);
  depot_write_kernel<<<1, 256, 0, stream>>>(dpar, depo, CThi, CTlo);

  // 6. output projection with fused un-sort scatter
  GemmArgs oa;
  oa.Whi[0] = Whi[3]; oa.Whi[1] = Whi[3]; oa.Whi[2] = Whi[3];
  oa.Wlo[0] = Wlo[3]; oa.Wlo[1] = Wlo[3]; oa.Wlo[2] = Wlo[3];
  oa.bias[0] = Wob; oa.bias[1] = Wob; oa.bias[2] = Wob;
  oa.C[0] = out; oa.C[1] = out; oa.C[2] = out;
  oa.Chi[0] = oa.Chi[1] = oa.Chi[2] = nullptr;
  oa.Clo[0] = oa.Clo[1] = oa.Clo[2] = nullptr;
  oa.split[0] = oa.split[1] = oa.split[2] = 0;
  gemm_bf16x3<64, 32, 1><<<dim3(E_ / 128, (BB_ * T_) / 64, 1), 256, 0, stream>>>(
      oa, CThi, CTlo, sidx);
}

// Round 8
// 200.484 us; speedup vs baseline: 1.3518x; 1.1620x over previous
//
#include <hip/hip_runtime.h>
#include <hip/hip_bf16.h>
#include <cmath>

// Problem constants (match reference)
constexpr int BB_ = 2;
constexpr int T_  = 1024;
constexpr int E_  = 1024;
constexpr int H_  = 8;
constexpr int HD_ = 128;
constexpr int WS_ = 64;
constexpr float TAU_   = 10.0f;
constexpr float SCALE_ = 0.08838834764831843f;  // 1/sqrt(128)

typedef __attribute__((ext_vector_type(8))) _Float16 half8;
typedef __attribute__((ext_vector_type(4))) _Float16 half4;
typedef __attribute__((ext_vector_type(4))) float floatx4;

// Split fp32 -> fp16 hi + fp16 lo. x == hi + lo to ~2^-22 rel.
struct HfPair { _Float16 hi, lo; };
__device__ inline HfPair f2h_pair(float x) {
  HfPair r;
  r.hi = (_Float16)x;
  r.lo = (_Float16)(x - (float)r.hi);
  return r;
}

// ---------------------------------------------------------------------------
// Kernel 1: exact stable argsort via rank counting, grid-parallel.
// ---------------------------------------------------------------------------
constexpr int STB_ = 16;  // t-values per block

__global__ __launch_bounds__(256) void sort_rank_kernel(
    const float* __restrict__ coord, int* __restrict__ sidx,
    float* __restrict__ c_s, int* __restrict__ depot) {
  __shared__ float c[T_];
  const int nb = T_ / STB_;
  const int b = blockIdx.x / nb;
  const int t0 = (blockIdx.x % nb) * STB_;
  const float* cb = coord + (size_t)b * T_;
  for (int i = threadIdx.x; i < T_; i += 256) c[i] = cb[i];
  __syncthreads();
  const int tl = threadIdx.x >> 4;
  const int ch = threadIdx.x & 15;
  const int t = t0 + tl;
  const float ct = c[t];
  int rank = 0;
  const int u0 = ch * (T_ / 16);
  #pragma unroll 8
  for (int i = 0; i < T_ / 16; ++i) {
    const int u = u0 + i;
    const float cu = c[u];
    rank += (cu < ct) || (cu == ct && u < t);
  }
  #pragma unroll
  for (int o = 8; o > 0; o >>= 1) rank += __shfl_xor(rank, o);
  if (ch == 0) {
    sidx[b * T_ + rank] = t;
    c_s[b * T_ + rank] = ct;
    if (t == 0) depot[b] = rank;
  }
}

// ---------------------------------------------------------------------------
// Kernel 2a: gather (h -> h_s) fused with fp32 -> fp16 hi/lo split.
// ---------------------------------------------------------------------------
__global__ __launch_bounds__(256) void convert_gather_h(
    const float* __restrict__ h, const int* __restrict__ sidx,
    _Float16* __restrict__ Ahi, _Float16* __restrict__ Alo) {
  const int gr = blockIdx.x;
  const int srow = (gr & ~(T_ - 1)) + sidx[gr];
  const float4 v = *(const float4*)(h + (size_t)srow * E_ + threadIdx.x * 4);
  half4 hv, lv;
  HfPair p0 = f2h_pair(v.x), p1 = f2h_pair(v.y);
  HfPair p2 = f2h_pair(v.z), p3 = f2h_pair(v.w);
  hv.x = p0.hi; hv.y = p1.hi; hv.z = p2.hi; hv.w = p3.hi;
  lv.x = p0.lo; lv.y = p1.lo; lv.z = p2.lo; lv.w = p3.lo;
  const size_t o = (size_t)gr * E_ + threadIdx.x * 4;
  *(half4*)(Ahi + o) = hv;
  *(half4*)(Alo + o) = lv;
}

// ---------------------------------------------------------------------------
// Kernel 2b: weight fp32 -> fp16 (single) for 4 matrices via grid.z.
// ---------------------------------------------------------------------------
struct WConv {
  const float* src[4];
  _Float16* dst[4];
};

__global__ __launch_bounds__(256) void convert_w_kernel(WConv a) {
  const int z = blockIdx.z;
  const size_t idx = ((size_t)blockIdx.x * 256 + threadIdx.x) * 4;
  const float4 v = *(const float4*)(a.src[z] + idx);
  half4 hv;
  hv.x = (_Float16)v.x; hv.y = (_Float16)v.y;
  hv.z = (_Float16)v.z; hv.w = (_Float16)v.w;
  *(half4*)(a.dst[z] + idx) = hv;
}

// ---------------------------------------------------------------------------
// Kernel 3: fp16 2-term MFMA GEMM.
//   C[m,n] = (Ahi+Alo)[m,:] . Wf16[n,:] + bias[n]
// A kept exact as fp16 pair; W quantized once to fp16 (err ~2^-12 rel of W —
// the only GEMM error term). Tile BM x BN, BK=32, 4 waves 2x2, wave tile
// (BM/2)x(BN/2). FP16OUT: Q/K/V stored as single fp16; else fp32.
// SCATTER stores row m to (batch + sidx[m]) (fused un-sort).
// ---------------------------------------------------------------------------
struct GemmArgs {
  const _Float16* W[3];
  const float* bias[3];
  float* Cf[3];
  _Float16* Ch[3];
};

constexpr int LP_ = 56;  // padded LDS row stride (halves): 112 B, bank-rotating

template <int BM, int BN, int SCATTER, int FP16OUT>
__global__ __launch_bounds__(256, 2) void gemm_f16x2(
    GemmArgs args, const _Float16* __restrict__ Ahi,
    const _Float16* __restrict__ Alo, const int* __restrict__ sidx) {
  constexpr int TMI = BM / 32;
  constexpr int TNI = BN / 32;
  const _Float16* __restrict__ W = args.W[blockIdx.z];
  const float* __restrict__ bias = args.bias[blockIdx.z];

  __shared__ _Float16 As_hi[BM][LP_], As_lo[BM][LP_], Bs[BN][LP_];

  const int tid = threadIdx.x;
  const int wv = tid >> 6, lane = tid & 63;
  const int kq = lane >> 4, ln15 = lane & 15;
  const int wm0 = (wv >> 1) * (BM / 2), wn0 = (wv & 1) * (BN / 2);
  const int m0 = blockIdx.y * BM, n0 = blockIdx.x * BN;

  floatx4 acc[TMI][TNI];
  #pragma unroll
  for (int i = 0; i < TMI; ++i)
    #pragma unroll
    for (int j = 0; j < TNI; ++j) acc[i][j] = (floatx4){0.f, 0.f, 0.f, 0.f};

  for (int k0 = 0; k0 < E_; k0 += 32) {
    #pragma unroll
    for (int i = 0; i < BM * 4 / 256; ++i) {
      const int idx = tid + 256 * i;
      const int r = idx >> 2, c = idx & 3;
      const size_t g = (size_t)(m0 + r) * E_ + k0 + c * 8;
      *(half8*)&As_hi[r][c * 8] = *(const half8*)(Ahi + g);
      *(half8*)&As_lo[r][c * 8] = *(const half8*)(Alo + g);
    }
    #pragma unroll
    for (int i = 0; i < BN * 4 / 256; ++i) {
      const int idx = tid + 256 * i;
      const int r = idx >> 2, c = idx & 3;
      const size_t g = (size_t)(n0 + r) * E_ + k0 + c * 8;
      *(half8*)&Bs[r][c * 8] = *(const half8*)(W + g);
    }
    __syncthreads();

    half8 ah[TMI], al[TMI], bf[TNI];
    #pragma unroll
    for (int mi = 0; mi < TMI; ++mi) {
      ah[mi] = *(const half8*)&As_hi[wm0 + mi * 16 + ln15][kq * 8];
      al[mi] = *(const half8*)&As_lo[wm0 + mi * 16 + ln15][kq * 8];
    }
    #pragma unroll
    for (int ni = 0; ni < TNI; ++ni)
      bf[ni] = *(const half8*)&Bs[wn0 + ni * 16 + ln15][kq * 8];
    #pragma unroll
    for (int mi = 0; mi < TMI; ++mi)
      #pragma unroll
      for (int ni = 0; ni < TNI; ++ni) {
        acc[mi][ni] = __builtin_amdgcn_mfma_f32_16x16x32_f16(
            ah[mi], bf[ni], acc[mi][ni], 0, 0, 0);
        acc[mi][ni] = __builtin_amdgcn_mfma_f32_16x16x32_f16(
            al[mi], bf[ni], acc[mi][ni], 0, 0, 0);
      }
    __syncthreads();
  }

  float* __restrict__ Cf = args.Cf[blockIdx.z];
  _Float16* __restrict__ Ch = args.Ch[blockIdx.z];
  #pragma unroll
  for (int ni = 0; ni < TNI; ++ni) {
    const int col = n0 + wn0 + ni * 16 + ln15;
    const float bv = bias[col];
    #pragma unroll
    for (int mi = 0; mi < TMI; ++mi) {
      #pragma unroll
      for (int r = 0; r < 4; ++r) {
        const int m = m0 + wm0 + mi * 16 + kq * 4 + r;
        const int orow = SCATTER ? ((m & ~(T_ - 1)) + sidx[m]) : m;
        const float val = acc[mi][ni][r] + bv;
        if (FP16OUT) {
          Ch[(size_t)orow * E_ + col] = (_Float16)val;
        } else {
          Cf[(size_t)orow * E_ + col] = val;
        }
      }
    }
  }
}

// ---------------------------------------------------------------------------
// Kernel 4: local sliding-window attention — fp16 MFMA QK^T + slot-unified PV.
// Q/K/V fp16-single (exact stored values; scores are exact dots of them).
// QTm=16 queries/block -> grid 1024. Slots 0..79 window, slot 80 = depot.
// ---------------------------------------------------------------------------
constexpr int QTm_ = 16;
constexpr int NSL_ = 80;

__global__ __launch_bounds__(256) void attn_local_kernel(
    const _Float16* __restrict__ Qh, const _Float16* __restrict__ Kh,
    const _Float16* __restrict__ Vh, const float* __restrict__ c_s,
    const int* __restrict__ depot, _Float16* __restrict__ CTXhi,
    _Float16* __restrict__ CTXlo) {
  __shared__ float sc[QTm_][88];    // [query][slot]; slot 80 = depot
  __shared__ float cw[NSL_];
  __shared__ float cq[QTm_];
  __shared__ float kdep[HD_];

  const int tid = threadIdx.x;
  const int ntq = T_ / QTm_;                 // 64
  const int tq = blockIdx.x % ntq;
  const int bh = blockIdx.x / ntq;
  const int h = bh % H_, b = bh / H_;
  const int t0 = tq * QTm_;
  const int dep = depot[b];
  const int smin = min(max(t0 - 32, 0), T_ - WS_);
  const size_t baseBH = ((size_t)b * T_) * E_ + (size_t)h * HD_;

  if (tid < NSL_) {
    cw[tid] = c_s[b * T_ + min(smin + tid, T_ - 1)];
  } else if (tid < NSL_ + QTm_) {
    cq[tid - NSL_] = c_s[b * T_ + t0 + tid - NSL_];
  } else if (tid >= 128) {
    const int d = tid - 128;
    kdep[d] = (float)Kh[baseBH + (size_t)dep * E_ + d];
  }
  __syncthreads();

  const int wv = tid >> 6, lane = tid & 63;
  const int ln15 = lane & 15, kq = lane >> 4;

  // ---- MFMA scores: wave w covers key tiles {w} (+ tile 4 for wave 0) ----
  {
    const size_t qoff = baseBH + (size_t)(t0 + ln15) * E_ + kq * 8;
    half8 aH[4];
    #pragma unroll
    for (int ks = 0; ks < 4; ++ks)
      aH[ks] = *(const half8*)(Qh + qoff + ks * 32);
    for (int kt = wv; kt < 5; kt += 4) {
      const int key = min(smin + kt * 16 + ln15, T_ - 1);
      const size_t koff = baseBH + (size_t)key * E_ + kq * 8;
      floatx4 acc = (floatx4){0.f, 0.f, 0.f, 0.f};
      #pragma unroll
      for (int ks = 0; ks < 4; ++ks) {
        const half8 b8 = *(const half8*)(Kh + koff + ks * 32);
        acc = __builtin_amdgcn_mfma_f32_16x16x32_f16(aH[ks], b8, acc, 0, 0, 0);
      }
      #pragma unroll
      for (int r = 0; r < 4; ++r)
        sc[kq * 4 + r][kt * 16 + ln15] = acc[r];
    }
  }

  // ---- depot column raw scores (vector dot; wave handles 4 queries) ----
  const float cdep = c_s[b * T_ + dep];
  #pragma unroll
  for (int qi = 0; qi < 4; ++qi) {
    const int q = wv * 4 + qi;
    const int t = t0 + q;
    const size_t qo2 = baseBH + (size_t)t * E_;
    const float q1 = (float)Qh[qo2 + lane];
    const float q2 = (float)Qh[qo2 + 64 + lane];
    float part = fmaf(q1, kdep[lane], q2 * kdep[lane + 64]);
    #pragma unroll
    for (int o = 32; o > 0; o >>= 1) part += __shfl_xor(part, o);
    if (lane == 0) {
      const int st = min(max(t - 32, 0), T_ - WS_);
      const bool masked = (unsigned)(dep - st) < (unsigned)WS_;
      const float dd = cdep - cq[q];
      sc[q][80] = masked ? -3.0e38f
                         : part * SCALE_ - dd * dd * (1.0f / TAU_);
    }
  }
  __syncthreads();

  // ---- softmax (wave handles 4 queries); invalid slots get weight 0 ----
  #pragma unroll
  for (int qi = 0; qi < 4; ++qi) {
    const int q = wv * 4 + qi;
    const int t = t0 + q;
    const int st = min(max(t - 32, 0), T_ - WS_);
    const int base = st - smin;            // 0..16
    const float cqv = cq[q];
    const int j1 = lane;
    float s1 = -3.0e38f;
    if (j1 >= base && j1 < base + WS_) {
      const float dd = cw[j1] - cqv;
      s1 = sc[q][j1] * SCALE_ - dd * dd * (1.0f / TAU_);
    }
    const int j2 = 64 + lane;
    float s2 = -3.0e38f;
    if (lane < 16 && j2 >= base && j2 < base + WS_) {
      const float dd = cw[j2] - cqv;
      s2 = sc[q][j2] * SCALE_ - dd * dd * (1.0f / TAU_);
    }
    const float sdep = sc[q][80];
    float m = fmaxf(s1, s2);
    #pragma unroll
    for (int o = 32; o > 0; o >>= 1) m = fmaxf(m, __shfl_xor(m, o));
    m = fmaxf(m, sdep);
    const float e1 = expf(s1 - m);
    const float e2 = (lane < 16) ? expf(s2 - m) : 0.f;
    float sum = e1 + e2;
    #pragma unroll
    for (int o = 32; o > 0; o >>= 1) sum += __shfl_xor(sum, o);
    const float edep = expf(sdep - m);
    sum += edep;
    const float inv = 1.0f / sum;
    sc[q][j1] = e1 * inv;
    if (lane < 16) sc[q][j2] = e2 * inv;
    if (lane == 0) sc[q][80] = edep * inv;
  }
  __syncthreads();

  // ---- PV: one pass over 81 slots; V (fp16) loaded once per (slot, lane) ----
  {
    const int d1 = lane, d2 = lane + 64;
    float acc0[4], acc1[4];
    #pragma unroll
    for (int qi = 0; qi < 4; ++qi) { acc0[qi] = 0.f; acc1[qi] = 0.f; }
    for (int j = 0; j <= NSL_; ++j) {
      const int row = (j < NSL_) ? min(smin + j, T_ - 1) : dep;
      const size_t vo = baseBH + (size_t)row * E_;
      const float v1 = (float)Vh[vo + d1];
      const float v2 = (float)Vh[vo + d2];
      #pragma unroll
      for (int qi = 0; qi < 4; ++qi) {
        const float w = sc[wv * 4 + qi][j];
        acc0[qi] = fmaf(w, v1, acc0[qi]);
        acc1[qi] = fmaf(w, v2, acc1[qi]);
      }
    }
    #pragma unroll
    for (int qi = 0; qi < 4; ++qi) {
      const int t = t0 + wv * 4 + qi;
      const size_t co = baseBH + (size_t)t * E_;
      HfPair p1 = f2h_pair(acc0[qi]);
      HfPair p2 = f2h_pair(acc1[qi]);
      CTXhi[co + d1] = p1.hi;  CTXlo[co + d1] = p1.lo;
      CTXhi[co + d2] = p2.hi;  CTXlo[co + d2] = p2.lo;
    }
  }
}

// ---------------------------------------------------------------------------
// Depot attention, grid-parallel (Q/K/V fp16-single).
// ---------------------------------------------------------------------------
constexpr int DCH_ = 16;
constexpr int VSP_ = 8;

__global__ __launch_bounds__(256) void depot_scores_kernel(
    const _Float16* __restrict__ Qh, const _Float16* __restrict__ Kh,
    const float* __restrict__ c_s, const int* __restrict__ depot,
    float* __restrict__ scg) {
  const int chunk = blockIdx.x % DCH_;
  const int bh = blockIdx.x / DCH_;
  const int h = bh % H_, b = bh / H_;
  const int tid = threadIdx.x, wv = tid >> 6, lane = tid & 63;
  const int dep = depot[b];
  const size_t baseBH = ((size_t)b * T_) * E_ + (size_t)h * HD_;
  __shared__ float qd[HD_];
  if (tid < HD_) qd[tid] = (float)Qh[baseBH + (size_t)dep * E_ + tid];
  __syncthreads();
  const float cdep = c_s[b * T_ + dep];
  constexpr int KPB = T_ / DCH_;
  const int k0 = chunk * KPB + wv * (KPB / 4);
  #pragma unroll 4
  for (int i = 0; i < KPB / 4; ++i) {
    const int k = k0 + i;
    const size_t ko = baseBH + (size_t)k * E_;
    const float k1 = (float)Kh[ko + lane];
    const float k2 = (float)Kh[ko + 64 + lane];
    float part = fmaf(qd[lane], k1, qd[lane + 64] * k2);
    #pragma unroll
    for (int o = 32; o > 0; o >>= 1) part += __shfl_xor(part, o);
    if (lane == 0) {
      const float dd = c_s[b * T_ + k] - cdep;
      scg[bh * T_ + k] = part * SCALE_ - dd * dd * (1.0f / TAU_);
    }
  }
}

__global__ __launch_bounds__(256) void depot_softmax_kernel(
    float* __restrict__ scg) {
  __shared__ float sc[T_];
  __shared__ float red[4];
  const int bh = blockIdx.x;
  const int tid = threadIdx.x, wv = tid >> 6, lane = tid & 63;
  float* s = scg + bh * T_;
  float lm = -3.0e38f;
  for (int k = tid; k < T_; k += 256) { sc[k] = s[k]; lm = fmaxf(lm, sc[k]); }
  #pragma unroll
  for (int o = 32; o > 0; o >>= 1) lm = fmaxf(lm, __shfl_xor(lm, o));
  if (lane == 0) red[wv] = lm;
  __syncthreads();
  const float M = fmaxf(fmaxf(red[0], red[1]), fmaxf(red[2], red[3]));
  __syncthreads();
  float ls = 0.f;
  float ev[T_ / 256];
  #pragma unroll
  for (int i = 0; i < T_ / 256; ++i) {
    ev[i] = expf(sc[tid + 256 * i] - M);
    ls += ev[i];
  }
  #pragma unroll
  for (int o = 32; o > 0; o >>= 1) ls += __shfl_xor(ls, o);
  if (lane == 0) red[wv] = ls;
  __syncthreads();
  const float inv = 1.0f / (red[0] + red[1] + red[2] + red[3]);
  #pragma unroll
  for (int i = 0; i < T_ / 256; ++i) s[tid + 256 * i] = ev[i] * inv;
}

__global__ __launch_bounds__(256) void depot_ctx_kernel(
    const _Float16* __restrict__ Vh, const float* __restrict__ scg,
    float* __restrict__ part) {
  __shared__ float par[2][HD_];
  const int sp = blockIdx.x % VSP_;
  const int bh = blockIdx.x / VSP_;
  const int h = bh % H_, b = bh / H_;
  const int tid = threadIdx.x;
  const int d = tid & 127, kg = tid >> 7;
  const size_t baseBH = ((size_t)b * T_) * E_ + (size_t)h * HD_;
  constexpr int KPB = T_ / VSP_;
  const int k0 = sp * KPB + kg * (KPB / 2);
  const _Float16* vbase = Vh + baseBH + d;
  const float* a = scg + bh * T_;
  float acc = 0.f;
  #pragma unroll 8
  for (int k = k0; k < k0 + KPB / 2; ++k) {
    acc = fmaf(a[k], (float)vbase[(size_t)k * E_], acc);
  }
  par[kg][d] = acc;
  __syncthreads();
  if (tid < HD_) part[((size_t)sp * BB_ * H_ + bh) * HD_ + tid] =
      par[0][tid] + par[1][tid];
}

__global__ __launch_bounds__(256) void depot_write_kernel(
    const float* __restrict__ part, const int* __restrict__ depot,
    _Float16* __restrict__ CTXhi, _Float16* __restrict__ CTXlo) {
  for (int o = threadIdx.x; o < BB_ * H_ * HD_; o += 256) {
    const int bh = o >> 7, d = o & 127;
    float s = 0.f;
    #pragma unroll
    for (int sp = 0; sp < VSP_; ++sp)
      s += part[((size_t)sp * BB_ * H_ + bh) * HD_ + d];
    const int h = bh % H_, b = bh / H_;
    const int dep = depot[b];
    HfPair pr = f2h_pair(s);
    const size_t idx = ((size_t)b * T_ + dep) * E_ + (size_t)h * HD_ + d;
    CTXhi[idx] = pr.hi;
    CTXlo[idx] = pr.lo;
  }
}

// ---------------------------------------------------------------------------
extern "C" void kernel_launch(void* const* d_in, const int* in_sizes, int n_in,
                              void* d_out, int out_size, void* d_ws, size_t ws_size,
                              hipStream_t stream) {
  const float* h     = (const float*)d_in[0];
  const float* coord = (const float*)d_in[1];
  const float* Wq    = (const float*)d_in[2];
  const float* Wqb   = (const float*)d_in[3];
  const float* Wk    = (const float*)d_in[4];
  const float* Wkb   = (const float*)d_in[5];
  const float* Wv    = (const float*)d_in[6];
  const float* Wvb   = (const float*)d_in[7];
  const float* Wo    = (const float*)d_in[8];
  const float* Wob   = (const float*)d_in[9];
  float* out = (float*)d_out;

  char* ws = (char*)d_ws;
  const size_t MATH_ = (size_t)BB_ * T_ * E_ * 2;  // 4 MB fp16
  const size_t WB   = (size_t)E_ * E_ * 2;         // 2 MB fp16
  size_t off = 0;
  _Float16* Qh  = (_Float16*)(ws + off); off += MATH_;
  _Float16* Kh  = (_Float16*)(ws + off); off += MATH_;
  _Float16* Vh  = (_Float16*)(ws + off); off += MATH_;
  _Float16* Ahi = (_Float16*)(ws + off); off += MATH_;
  _Float16* Alo = (_Float16*)(ws + off); off += MATH_;
  _Float16* CThi = (_Float16*)(ws + off); off += MATH_;
  _Float16* CTlo = (_Float16*)(ws + off); off += MATH_;
  _Float16* Wh[4];
  for (int i = 0; i < 4; ++i) { Wh[i] = (_Float16*)(ws + off); off += WB; }
  float* c_s = (float*)(ws + off); off += (size_t)BB_ * T_ * 4;
  int* sidx  = (int*)(ws + off);   off += (size_t)BB_ * T_ * 4;
  int* depo  = (int*)(ws + off);   off += 256;
  float* scg  = (float*)(ws + off); off += (size_t)BB_ * H_ * T_ * 4;
  float* dpar = (float*)(ws + off); off += (size_t)VSP_ * BB_ * H_ * HD_ * 4;

  // 1. stable sort by coordinate (grid-parallel rank counting)
  sort_rank_kernel<<<BB_ * (T_ / STB_), 256, 0, stream>>>(coord, sidx, c_s, depo);

  // 2a. gather + fp16 hi/lo split of h
  convert_gather_h<<<BB_ * T_, 256, 0, stream>>>(h, sidx, Ahi, Alo);

  // 2b. weights -> fp16 single
  WConv wc;
  wc.src[0] = Wq; wc.src[1] = Wk; wc.src[2] = Wv; wc.src[3] = Wo;
  for (int i = 0; i < 4; ++i) wc.dst[i] = Wh[i];
  convert_w_kernel<<<dim3(E_ * E_ / 1024, 1, 4), 256, 0, stream>>>(wc);

  // 3. QKV projections: 128x64 tiles -> grid 768 (3 blocks/CU); fp16 out
  GemmArgs qa;
  qa.W[0] = Wh[0]; qa.W[1] = Wh[1]; qa.W[2] = Wh[2];
  qa.bias[0] = Wqb; qa.bias[1] = Wkb; qa.bias[2] = Wvb;
  qa.Cf[0] = qa.Cf[1] = qa.Cf[2] = nullptr;
  qa.Ch[0] = Qh; qa.Ch[1] = Kh; qa.Ch[2] = Vh;
  gemm_f16x2<128, 64, 0, 1><<<dim3(E_ / 64, (BB_ * T_) / 128, 3), 256, 0, stream>>>(
      qa, Ahi, Alo, sidx);

  // 4. sliding-window attention (fp16 MFMA QK^T, slot-unified PV)
  attn_local_kernel<<<BB_ * H_ * (T_ / QTm_), 256, 0, stream>>>(
      Qh, Kh, Vh, c_s, depo, CThi, CTlo);

  // 5. depot full attention, grid-parallel (overwrites ctx depot rows)
  depot_scores_kernel<<<BB_ * H_ * DCH_, 256, 0, stream>>>(
      Qh, Kh, c_s, depo, scg);
  depot_softmax_kernel<<<BB_ * H_, 256, 0, stream>>>(scg);
  depot_ctx_kernel<<<BB_ * H_ * VSP_, 256, 0, stream>>>(Vh, scg, dpar);
  depot_write_kernel<<<1, 256, 0, stream>>>(dpar, depo, CThi, CTlo);

  // 6. output projection: 64x64 tiles -> grid 512 (2 blocks/CU); fp32 out,
  //    fused un-sort scatter
  GemmArgs oa;
  oa.W[0] = oa.W[1] = oa.W[2] = Wh[3];
  oa.bias[0] = oa.bias[1] = oa.bias[2] = Wob;
  oa.Cf[0] = oa.Cf[1] = oa.Cf[2] = out;
  oa.Ch[0] = oa.Ch[1] = oa.Ch[2] = nullptr;
  gemm_f16x2<64, 64, 1, 0><<<dim3(E_ / 64, (BB_ * T_) / 64, 1), 256, 0, stream>>>(
      oa, CThi, CTlo, sidx);
}

// Round 9
// 181.161 us; speedup vs baseline: 1.4959x; 1.1067x over previous
//
#include <hip/hip_runtime.h>
#include <hip/hip_bf16.h>
#include <cmath>

// Problem constants (match reference)
constexpr int BB_ = 2;
constexpr int T_  = 1024;
constexpr int E_  = 1024;
constexpr int H_  = 8;
constexpr int HD_ = 128;
constexpr int WS_ = 64;
constexpr float TAU_   = 10.0f;
constexpr float SCALE_ = 0.08838834764831843f;  // 1/sqrt(128)

typedef __attribute__((ext_vector_type(8))) _Float16 half8;
typedef __attribute__((ext_vector_type(4))) _Float16 half4;
typedef __attribute__((ext_vector_type(4))) float floatx4;

// ---------------------------------------------------------------------------
// Kernel 1: exact stable argsort via rank counting, grid-parallel.
// ---------------------------------------------------------------------------
constexpr int STB_ = 16;  // t-values per block

__global__ __launch_bounds__(256) void sort_rank_kernel(
    const float* __restrict__ coord, int* __restrict__ sidx,
    float* __restrict__ c_s, int* __restrict__ depot) {
  __shared__ float c[T_];
  const int nb = T_ / STB_;
  const int b = blockIdx.x / nb;
  const int t0 = (blockIdx.x % nb) * STB_;
  const float* cb = coord + (size_t)b * T_;
  for (int i = threadIdx.x; i < T_; i += 256) c[i] = cb[i];
  __syncthreads();
  const int tl = threadIdx.x >> 4;
  const int ch = threadIdx.x & 15;
  const int t = t0 + tl;
  const float ct = c[t];
  int rank = 0;
  const int u0 = ch * (T_ / 16);
  #pragma unroll 8
  for (int i = 0; i < T_ / 16; ++i) {
    const int u = u0 + i;
    const float cu = c[u];
    rank += (cu < ct) || (cu == ct && u < t);
  }
  #pragma unroll
  for (int o = 8; o > 0; o >>= 1) rank += __shfl_xor(rank, o);
  if (ch == 0) {
    sidx[b * T_ + rank] = t;
    c_s[b * T_ + rank] = ct;
    if (t == 0) depot[b] = rank;
  }
}

// ---------------------------------------------------------------------------
// Kernel 2a: gather (h -> h_s) fused with fp32 -> fp16 convert (single).
// ---------------------------------------------------------------------------
__global__ __launch_bounds__(256) void convert_gather_h(
    const float* __restrict__ h, const int* __restrict__ sidx,
    _Float16* __restrict__ Ah) {
  const int gr = blockIdx.x;
  const int srow = (gr & ~(T_ - 1)) + sidx[gr];
  const float4 v = *(const float4*)(h + (size_t)srow * E_ + threadIdx.x * 4);
  half4 hv;
  hv.x = (_Float16)v.x; hv.y = (_Float16)v.y;
  hv.z = (_Float16)v.z; hv.w = (_Float16)v.w;
  *(half4*)(Ah + (size_t)gr * E_ + threadIdx.x * 4) = hv;
}

// ---------------------------------------------------------------------------
// Kernel 2b: weight fp32 -> fp16 (single) for 4 matrices via grid.z.
// ---------------------------------------------------------------------------
struct WConv {
  const float* src[4];
  _Float16* dst[4];
};

__global__ __launch_bounds__(256) void convert_w_kernel(WConv a) {
  const int z = blockIdx.z;
  const size_t idx = ((size_t)blockIdx.x * 256 + threadIdx.x) * 4;
  const float4 v = *(const float4*)(a.src[z] + idx);
  half4 hv;
  hv.x = (_Float16)v.x; hv.y = (_Float16)v.y;
  hv.z = (_Float16)v.z; hv.w = (_Float16)v.w;
  *(half4*)(a.dst[z] + idx) = hv;
}

// ---------------------------------------------------------------------------
// Kernel 3: fp16 single-term MFMA GEMM.
//   C[m,n] = A16[m,:] . W16[n,:] + bias[n]
// A and W both fp16 (quant err ~2^-12 rel each; measured-total absmax budget
// ~3e-3 vs 5.7e-3 threshold). Tile BM x BN, BK=32, 4 waves 2x2.
// FP16OUT: Q/K/V stored single fp16; else fp32. SCATTER: fused un-sort.
// ---------------------------------------------------------------------------
struct GemmArgs {
  const _Float16* W[3];
  const float* bias[3];
  float* Cf[3];
  _Float16* Ch[3];
};

constexpr int LP_ = 56;  // padded LDS row stride (halves): 112 B

template <int BM, int BN, int SCATTER, int FP16OUT>
__global__ __launch_bounds__(256, 2) void gemm_f16(
    GemmArgs args, const _Float16* __restrict__ A,
    const int* __restrict__ sidx) {
  constexpr int TMI = BM / 32;
  constexpr int TNI = BN / 32;
  const _Float16* __restrict__ W = args.W[blockIdx.z];
  const float* __restrict__ bias = args.bias[blockIdx.z];

  __shared__ _Float16 As[BM][LP_], Bs[BN][LP_];

  const int tid = threadIdx.x;
  const int wv = tid >> 6, lane = tid & 63;
  const int kq = lane >> 4, ln15 = lane & 15;
  const int wm0 = (wv >> 1) * (BM / 2), wn0 = (wv & 1) * (BN / 2);
  const int m0 = blockIdx.y * BM, n0 = blockIdx.x * BN;

  floatx4 acc[TMI][TNI];
  #pragma unroll
  for (int i = 0; i < TMI; ++i)
    #pragma unroll
    for (int j = 0; j < TNI; ++j) acc[i][j] = (floatx4){0.f, 0.f, 0.f, 0.f};

  for (int k0 = 0; k0 < E_; k0 += 32) {
    #pragma unroll
    for (int i = 0; i < BM * 4 / 256; ++i) {
      const int idx = tid + 256 * i;
      const int r = idx >> 2, c = idx & 3;
      *(half8*)&As[r][c * 8] =
          *(const half8*)(A + (size_t)(m0 + r) * E_ + k0 + c * 8);
    }
    #pragma unroll
    for (int i = 0; i < BN * 4 / 256; ++i) {
      const int idx = tid + 256 * i;
      const int r = idx >> 2, c = idx & 3;
      *(half8*)&Bs[r][c * 8] =
          *(const half8*)(W + (size_t)(n0 + r) * E_ + k0 + c * 8);
    }
    __syncthreads();

    half8 ah[TMI], bf[TNI];
    #pragma unroll
    for (int mi = 0; mi < TMI; ++mi)
      ah[mi] = *(const half8*)&As[wm0 + mi * 16 + ln15][kq * 8];
    #pragma unroll
    for (int ni = 0; ni < TNI; ++ni)
      bf[ni] = *(const half8*)&Bs[wn0 + ni * 16 + ln15][kq * 8];
    #pragma unroll
    for (int mi = 0; mi < TMI; ++mi)
      #pragma unroll
      for (int ni = 0; ni < TNI; ++ni)
        acc[mi][ni] = __builtin_amdgcn_mfma_f32_16x16x32_f16(
            ah[mi], bf[ni], acc[mi][ni], 0, 0, 0);
    __syncthreads();
  }

  float* __restrict__ Cf = args.Cf[blockIdx.z];
  _Float16* __restrict__ Ch = args.Ch[blockIdx.z];
  #pragma unroll
  for (int ni = 0; ni < TNI; ++ni) {
    const int col = n0 + wn0 + ni * 16 + ln15;
    const float bv = bias[col];
    #pragma unroll
    for (int mi = 0; mi < TMI; ++mi) {
      #pragma unroll
      for (int r = 0; r < 4; ++r) {
        const int m = m0 + wm0 + mi * 16 + kq * 4 + r;
        const int orow = SCATTER ? ((m & ~(T_ - 1)) + sidx[m]) : m;
        const float val = acc[mi][ni][r] + bv;
        if (FP16OUT) {
          Ch[(size_t)orow * E_ + col] = (_Float16)val;
        } else {
          Cf[(size_t)orow * E_ + col] = val;
        }
      }
    }
  }
}

// ---------------------------------------------------------------------------
// Kernel 4: local sliding-window attention — fp16 MFMA QK^T + slot-unified PV.
// QTm=16 queries/block -> grid 1024. Slots 0..79 window, slot 80 = depot.
// ---------------------------------------------------------------------------
constexpr int QTm_ = 16;
constexpr int NSL_ = 80;

__global__ __launch_bounds__(256) void attn_local_kernel(
    const _Float16* __restrict__ Qh, const _Float16* __restrict__ Kh,
    const _Float16* __restrict__ Vh, const float* __restrict__ c_s,
    const int* __restrict__ depot, _Float16* __restrict__ CTh) {
  __shared__ float sc[QTm_][88];    // [query][slot]; slot 80 = depot
  __shared__ float cw[NSL_];
  __shared__ float cq[QTm_];
  __shared__ float kdep[HD_];

  const int tid = threadIdx.x;
  const int ntq = T_ / QTm_;                 // 64
  const int tq = blockIdx.x % ntq;
  const int bh = blockIdx.x / ntq;
  const int h = bh % H_, b = bh / H_;
  const int t0 = tq * QTm_;
  const int dep = depot[b];
  const int smin = min(max(t0 - 32, 0), T_ - WS_);
  const size_t baseBH = ((size_t)b * T_) * E_ + (size_t)h * HD_;

  if (tid < NSL_) {
    cw[tid] = c_s[b * T_ + min(smin + tid, T_ - 1)];
  } else if (tid < NSL_ + QTm_) {
    cq[tid - NSL_] = c_s[b * T_ + t0 + tid - NSL_];
  } else if (tid >= 128) {
    const int d = tid - 128;
    kdep[d] = (float)Kh[baseBH + (size_t)dep * E_ + d];
  }
  __syncthreads();

  const int wv = tid >> 6, lane = tid & 63;
  const int ln15 = lane & 15, kq = lane >> 4;

  // ---- MFMA scores: wave w covers key tiles {w} (+ tile 4 for wave 0) ----
  {
    const size_t qoff = baseBH + (size_t)(t0 + ln15) * E_ + kq * 8;
    half8 aH[4];
    #pragma unroll
    for (int ks = 0; ks < 4; ++ks)
      aH[ks] = *(const half8*)(Qh + qoff + ks * 32);
    for (int kt = wv; kt < 5; kt += 4) {
      const int key = min(smin + kt * 16 + ln15, T_ - 1);
      const size_t koff = baseBH + (size_t)key * E_ + kq * 8;
      floatx4 acc = (floatx4){0.f, 0.f, 0.f, 0.f};
      #pragma unroll
      for (int ks = 0; ks < 4; ++ks) {
        const half8 b8 = *(const half8*)(Kh + koff + ks * 32);
        acc = __builtin_amdgcn_mfma_f32_16x16x32_f16(aH[ks], b8, acc, 0, 0, 0);
      }
      #pragma unroll
      for (int r = 0; r < 4; ++r)
        sc[kq * 4 + r][kt * 16 + ln15] = acc[r];
    }
  }

  // ---- depot column raw scores (vector dot; wave handles 4 queries) ----
  const float cdep = c_s[b * T_ + dep];
  #pragma unroll
  for (int qi = 0; qi < 4; ++qi) {
    const int q = wv * 4 + qi;
    const int t = t0 + q;
    const size_t qo2 = baseBH + (size_t)t * E_;
    const float q1 = (float)Qh[qo2 + lane];
    const float q2 = (float)Qh[qo2 + 64 + lane];
    float part = fmaf(q1, kdep[lane], q2 * kdep[lane + 64]);
    #pragma unroll
    for (int o = 32; o > 0; o >>= 1) part += __shfl_xor(part, o);
    if (lane == 0) {
      const int st = min(max(t - 32, 0), T_ - WS_);
      const bool masked = (unsigned)(dep - st) < (unsigned)WS_;
      const float dd = cdep - cq[q];
      sc[q][80] = masked ? -3.0e38f
                         : part * SCALE_ - dd * dd * (1.0f / TAU_);
    }
  }
  __syncthreads();

  // ---- softmax (wave handles 4 queries); invalid slots get weight 0 ----
  #pragma unroll
  for (int qi = 0; qi < 4; ++qi) {
    const int q = wv * 4 + qi;
    const int t = t0 + q;
    const int st = min(max(t - 32, 0), T_ - WS_);
    const int base = st - smin;            // 0..16
    const float cqv = cq[q];
    const int j1 = lane;
    float s1 = -3.0e38f;
    if (j1 >= base && j1 < base + WS_) {
      const float dd = cw[j1] - cqv;
      s1 = sc[q][j1] * SCALE_ - dd * dd * (1.0f / TAU_);
    }
    const int j2 = 64 + lane;
    float s2 = -3.0e38f;
    if (lane < 16 && j2 >= base && j2 < base + WS_) {
      const float dd = cw[j2] - cqv;
      s2 = sc[q][j2] * SCALE_ - dd * dd * (1.0f / TAU_);
    }
    const float sdep = sc[q][80];
    float m = fmaxf(s1, s2);
    #pragma unroll
    for (int o = 32; o > 0; o >>= 1) m = fmaxf(m, __shfl_xor(m, o));
    m = fmaxf(m, sdep);
    const float e1 = expf(s1 - m);
    const float e2 = (lane < 16) ? expf(s2 - m) : 0.f;
    float sum = e1 + e2;
    #pragma unroll
    for (int o = 32; o > 0; o >>= 1) sum += __shfl_xor(sum, o);
    const float edep = expf(sdep - m);
    sum += edep;
    const float inv = 1.0f / sum;
    sc[q][j1] = e1 * inv;
    if (lane < 16) sc[q][j2] = e2 * inv;
    if (lane == 0) sc[q][80] = edep * inv;
  }
  __syncthreads();

  // ---- PV: one pass over 81 slots; V (fp16) loaded once per (slot, lane) ----
  {
    const int d1 = lane, d2 = lane + 64;
    float acc0[4], acc1[4];
    #pragma unroll
    for (int qi = 0; qi < 4; ++qi) { acc0[qi] = 0.f; acc1[qi] = 0.f; }
    for (int j = 0; j <= NSL_; ++j) {
      const int row = (j < NSL_) ? min(smin + j, T_ - 1) : dep;
      const size_t vo = baseBH + (size_t)row * E_;
      const float v1 = (float)Vh[vo + d1];
      const float v2 = (float)Vh[vo + d2];
      #pragma unroll
      for (int qi = 0; qi < 4; ++qi) {
        const float w = sc[wv * 4 + qi][j];
        acc0[qi] = fmaf(w, v1, acc0[qi]);
        acc1[qi] = fmaf(w, v2, acc1[qi]);
      }
    }
    #pragma unroll
    for (int qi = 0; qi < 4; ++qi) {
      const int t = t0 + wv * 4 + qi;
      const size_t co = baseBH + (size_t)t * E_;
      CTh[co + d1] = (_Float16)acc0[qi];
      CTh[co + d2] = (_Float16)acc1[qi];
    }
  }
}

// ---------------------------------------------------------------------------
// Depot attention, grid-parallel (Q/K/V fp16-single).
// ---------------------------------------------------------------------------
constexpr int DCH_ = 16;
constexpr int VSP_ = 8;

__global__ __launch_bounds__(256) void depot_scores_kernel(
    const _Float16* __restrict__ Qh, const _Float16* __restrict__ Kh,
    const float* __restrict__ c_s, const int* __restrict__ depot,
    float* __restrict__ scg) {
  const int chunk = blockIdx.x % DCH_;
  const int bh = blockIdx.x / DCH_;
  const int h = bh % H_, b = bh / H_;
  const int tid = threadIdx.x, wv = tid >> 6, lane = tid & 63;
  const int dep = depot[b];
  const size_t baseBH = ((size_t)b * T_) * E_ + (size_t)h * HD_;
  __shared__ float qd[HD_];
  if (tid < HD_) qd[tid] = (float)Qh[baseBH + (size_t)dep * E_ + tid];
  __syncthreads();
  const float cdep = c_s[b * T_ + dep];
  constexpr int KPB = T_ / DCH_;
  const int k0 = chunk * KPB + wv * (KPB / 4);
  #pragma unroll 4
  for (int i = 0; i < KPB / 4; ++i) {
    const int k = k0 + i;
    const size_t ko = baseBH + (size_t)k * E_;
    const float k1 = (float)Kh[ko + lane];
    const float k2 = (float)Kh[ko + 64 + lane];
    float part = fmaf(qd[lane], k1, qd[lane + 64] * k2);
    #pragma unroll
    for (int o = 32; o > 0; o >>= 1) part += __shfl_xor(part, o);
    if (lane == 0) {
      const float dd = c_s[b * T_ + k] - cdep;
      scg[bh * T_ + k] = part * SCALE_ - dd * dd * (1.0f / TAU_);
    }
  }
}

__global__ __launch_bounds__(256) void depot_softmax_kernel(
    float* __restrict__ scg) {
  __shared__ float sc[T_];
  __shared__ float red[4];
  const int bh = blockIdx.x;
  const int tid = threadIdx.x, wv = tid >> 6, lane = tid & 63;
  float* s = scg + bh * T_;
  float lm = -3.0e38f;
  for (int k = tid; k < T_; k += 256) { sc[k] = s[k]; lm = fmaxf(lm, sc[k]); }
  #pragma unroll
  for (int o = 32; o > 0; o >>= 1) lm = fmaxf(lm, __shfl_xor(lm, o));
  if (lane == 0) red[wv] = lm;
  __syncthreads();
  const float M = fmaxf(fmaxf(red[0], red[1]), fmaxf(red[2], red[3]));
  __syncthreads();
  float ls = 0.f;
  float ev[T_ / 256];
  #pragma unroll
  for (int i = 0; i < T_ / 256; ++i) {
    ev[i] = expf(sc[tid + 256 * i] - M);
    ls += ev[i];
  }
  #pragma unroll
  for (int o = 32; o > 0; o >>= 1) ls += __shfl_xor(ls, o);
  if (lane == 0) red[wv] = ls;
  __syncthreads();
  const float inv = 1.0f / (red[0] + red[1] + red[2] + red[3]);
  #pragma unroll
  for (int i = 0; i < T_ / 256; ++i) s[tid + 256 * i] = ev[i] * inv;
}

__global__ __launch_bounds__(256) void depot_ctx_kernel(
    const _Float16* __restrict__ Vh, const float* __restrict__ scg,
    float* __restrict__ part) {
  __shared__ float par[2][HD_];
  const int sp = blockIdx.x % VSP_;
  const int bh = blockIdx.x / VSP_;
  const int h = bh % H_, b = bh / H_;
  const int tid = threadIdx.x;
  const int d = tid & 127, kg = tid >> 7;
  const size_t baseBH = ((size_t)b * T_) * E_ + (size_t)h * HD_;
  constexpr int KPB = T_ / VSP_;
  const int k0 = sp * KPB + kg * (KPB / 2);
  const _Float16* vbase = Vh + baseBH + d;
  const float* a = scg + bh * T_;
  float acc = 0.f;
  #pragma unroll 8
  for (int k = k0; k < k0 + KPB / 2; ++k) {
    acc = fmaf(a[k], (float)vbase[(size_t)k * E_], acc);
  }
  par[kg][d] = acc;
  __syncthreads();
  if (tid < HD_) part[((size_t)sp * BB_ * H_ + bh) * HD_ + tid] =
      par[0][tid] + par[1][tid];
}

__global__ __launch_bounds__(256) void depot_write_kernel(
    const float* __restrict__ part, const int* __restrict__ depot,
    _Float16* __restrict__ CTh) {
  for (int o = threadIdx.x; o < BB_ * H_ * HD_; o += 256) {
    const int bh = o >> 7, d = o & 127;
    float s = 0.f;
    #pragma unroll
    for (int sp = 0; sp < VSP_; ++sp)
      s += part[((size_t)sp * BB_ * H_ + bh) * HD_ + d];
    const int h = bh % H_, b = bh / H_;
    const int dep = depot[b];
    CTh[((size_t)b * T_ + dep) * E_ + (size_t)h * HD_ + d] = (_Float16)s;
  }
}

// ---------------------------------------------------------------------------
extern "C" void kernel_launch(void* const* d_in, const int* in_sizes, int n_in,
                              void* d_out, int out_size, void* d_ws, size_t ws_size,
                              hipStream_t stream) {
  const float* h     = (const float*)d_in[0];
  const float* coord = (const float*)d_in[1];
  const float* Wq    = (const float*)d_in[2];
  const float* Wqb   = (const float*)d_in[3];
  const float* Wk    = (const float*)d_in[4];
  const float* Wkb   = (const float*)d_in[5];
  const float* Wv    = (const float*)d_in[6];
  const float* Wvb   = (const float*)d_in[7];
  const float* Wo    = (const float*)d_in[8];
  const float* Wob   = (const float*)d_in[9];
  float* out = (float*)d_out;

  char* ws = (char*)d_ws;
  const size_t MATH_ = (size_t)BB_ * T_ * E_ * 2;  // 4 MB fp16
  const size_t WB   = (size_t)E_ * E_ * 2;         // 2 MB fp16
  size_t off = 0;
  _Float16* Qh  = (_Float16*)(ws + off); off += MATH_;
  _Float16* Kh  = (_Float16*)(ws + off); off += MATH_;
  _Float16* Vh  = (_Float16*)(ws + off); off += MATH_;
  _Float16* Ah  = (_Float16*)(ws + off); off += MATH_;
  _Float16* CTh = (_Float16*)(ws + off); off += MATH_;
  _Float16* Wh[4];
  for (int i = 0; i < 4; ++i) { Wh[i] = (_Float16*)(ws + off); off += WB; }
  float* c_s = (float*)(ws + off); off += (size_t)BB_ * T_ * 4;
  int* sidx  = (int*)(ws + off);   off += (size_t)BB_ * T_ * 4;
  int* depo  = (int*)(ws + off);   off += 256;
  float* scg  = (float*)(ws + off); off += (size_t)BB_ * H_ * T_ * 4;
  float* dpar = (float*)(ws + off); off += (size_t)VSP_ * BB_ * H_ * HD_ * 4;

  // 1. stable sort by coordinate (grid-parallel rank counting)
  sort_rank_kernel<<<BB_ * (T_ / STB_), 256, 0, stream>>>(coord, sidx, c_s, depo);

  // 2a. gather + fp16 convert of h
  convert_gather_h<<<BB_ * T_, 256, 0, stream>>>(h, sidx, Ah);

  // 2b. weights -> fp16 single
  WConv wc;
  wc.src[0] = Wq; wc.src[1] = Wk; wc.src[2] = Wv; wc.src[3] = Wo;
  for (int i = 0; i < 4; ++i) wc.dst[i] = Wh[i];
  convert_w_kernel<<<dim3(E_ * E_ / 1024, 1, 4), 256, 0, stream>>>(wc);

  // 3. QKV projections: 128x64 tiles -> grid 768 (3 blocks/CU); fp16 out
  GemmArgs qa;
  qa.W[0] = Wh[0]; qa.W[1] = Wh[1]; qa.W[2] = Wh[2];
  qa.bias[0] = Wqb; qa.bias[1] = Wkb; qa.bias[2] = Wvb;
  qa.Cf[0] = qa.Cf[1] = qa.Cf[2] = nullptr;
  qa.Ch[0] = Qh; qa.Ch[1] = Kh; qa.Ch[2] = Vh;
  gemm_f16<128, 64, 0, 1><<<dim3(E_ / 64, (BB_ * T_) / 128, 3), 256, 0, stream>>>(
      qa, Ah, sidx);

  // 4. sliding-window attention (fp16 MFMA QK^T, slot-unified PV)
  attn_local_kernel<<<BB_ * H_ * (T_ / QTm_), 256, 0, stream>>>(
      Qh, Kh, Vh, c_s, depo, CTh);

  // 5. depot full attention, grid-parallel (overwrites ctx depot rows)
  depot_scores_kernel<<<BB_ * H_ * DCH_, 256, 0, stream>>>(
      Qh, Kh, c_s, depo, scg);
  depot_softmax_kernel<<<BB_ * H_, 256, 0, stream>>>(scg);
  depot_ctx_kernel<<<BB_ * H_ * VSP_, 256, 0, stream>>>(Vh, scg, dpar);
  depot_write_kernel<<<1, 256, 0, stream>>>(dpar, depo, CTh);

  // 6. output projection: 64x64 tiles -> grid 512 (2 blocks/CU); fp32 out,
  //    fused un-sort scatter
  GemmArgs oa;
  oa.W[0] = oa.W[1] = oa.W[2] = Wh[3];
  oa.bias[0] = oa.bias[1] = oa.bias[2] = Wob;
  oa.Cf[0] = oa.Cf[1] = oa.Cf[2] = out;
  oa.Ch[0] = oa.Ch[1] = oa.Ch[2] = nullptr;
  gemm_f16<64, 64, 1, 0><<<dim3(E_ / 64, (BB_ * T_) / 64, 1), 256, 0, stream>>>(
      oa, CTh, sidx);
}

// Round 10
// 169.413 us; speedup vs baseline: 1.5997x; 1.0693x over previous
//
#include <hip/hip_runtime.h>
#include <hip/hip_bf16.h>
#include <cmath>

// Problem constants (match reference)
constexpr int BB_ = 2;
constexpr int T_  = 1024;
constexpr int E_  = 1024;
constexpr int H_  = 8;
constexpr int HD_ = 128;
constexpr int WS_ = 64;
constexpr float TAU_   = 10.0f;
constexpr float SCALE_ = 0.08838834764831843f;  // 1/sqrt(128)

typedef __attribute__((ext_vector_type(8))) _Float16 half8;
typedef __attribute__((ext_vector_type(4))) _Float16 half4;
typedef __attribute__((ext_vector_type(2))) _Float16 half2v;
typedef __attribute__((ext_vector_type(4))) float floatx4;

// ---------------------------------------------------------------------------
// Kernel 1: exact stable argsort via rank counting, grid-parallel.
// ---------------------------------------------------------------------------
constexpr int STB_ = 16;  // t-values per block

__global__ __launch_bounds__(256) void sort_rank_kernel(
    const float* __restrict__ coord, int* __restrict__ sidx,
    float* __restrict__ c_s, int* __restrict__ depot) {
  __shared__ float c[T_];
  const int nb = T_ / STB_;
  const int b = blockIdx.x / nb;
  const int t0 = (blockIdx.x % nb) * STB_;
  const float* cb = coord + (size_t)b * T_;
  for (int i = threadIdx.x; i < T_; i += 256) c[i] = cb[i];
  __syncthreads();
  const int tl = threadIdx.x >> 4;
  const int ch = threadIdx.x & 15;
  const int t = t0 + tl;
  const float ct = c[t];
  int rank = 0;
  const int u0 = ch * (T_ / 16);
  #pragma unroll 8
  for (int i = 0; i < T_ / 16; ++i) {
    const int u = u0 + i;
    const float cu = c[u];
    rank += (cu < ct) || (cu == ct && u < t);
  }
  #pragma unroll
  for (int o = 8; o > 0; o >>= 1) rank += __shfl_xor(rank, o);
  if (ch == 0) {
    sidx[b * T_ + rank] = t;
    c_s[b * T_ + rank] = ct;
    if (t == 0) depot[b] = rank;
  }
}

// ---------------------------------------------------------------------------
// Kernel 2: weight fp32 -> fp16 (single) for 4 matrices via grid.z.
// ---------------------------------------------------------------------------
struct WConv {
  const float* src[4];
  _Float16* dst[4];
};

__global__ __launch_bounds__(256) void convert_w_kernel(WConv a) {
  const int z = blockIdx.z;
  const size_t idx = ((size_t)blockIdx.x * 256 + threadIdx.x) * 4;
  const float4 v = *(const float4*)(a.src[z] + idx);
  half4 hv;
  hv.x = (_Float16)v.x; hv.y = (_Float16)v.y;
  hv.z = (_Float16)v.z; hv.w = (_Float16)v.w;
  *(half4*)(a.dst[z] + idx) = hv;
}

// ---------------------------------------------------------------------------
// Kernel 3: fp16 MFMA GEMM.
//   GATHER=1: A is fp32 h, rows gathered via sidx and converted to fp16 in
//   staging (fuses the old convert_gather_h kernel). Else A fp16 direct.
//   FP16OUT: store fp16 (Q/K/V); else fp32. SCATTER: un-sort row scatter.
// Tile BM x BN, BK=32, 4 waves 2x2.
// ---------------------------------------------------------------------------
struct GemmArgs {
  const _Float16* W[3];
  const float* bias[3];
  float* Cf[3];
  _Float16* Ch[3];
};

constexpr int LP_ = 56;  // padded LDS row stride (halves): 112 B

template <int BM, int BN, int GATHER, int SCATTER, int FP16OUT>
__global__ __launch_bounds__(256, 2) void gemm_f16(
    GemmArgs args, const void* __restrict__ Av, const int* __restrict__ sidx) {
  constexpr int TMI = BM / 32;
  constexpr int TNI = BN / 32;
  const _Float16* __restrict__ W = args.W[blockIdx.z];
  const float* __restrict__ bias = args.bias[blockIdx.z];

  __shared__ _Float16 As[BM][LP_], Bs[BN][LP_];
  __shared__ int srow[BM];

  const int tid = threadIdx.x;
  const int wv = tid >> 6, lane = tid & 63;
  const int kq = lane >> 4, ln15 = lane & 15;
  const int wm0 = (wv >> 1) * (BM / 2), wn0 = (wv & 1) * (BN / 2);
  const int m0 = blockIdx.y * BM, n0 = blockIdx.x * BN;

  if (GATHER) {
    if (tid < BM) {
      const int gr = m0 + tid;
      srow[tid] = (gr & ~(T_ - 1)) + sidx[gr];
    }
    __syncthreads();
  }

  floatx4 acc[TMI][TNI];
  #pragma unroll
  for (int i = 0; i < TMI; ++i)
    #pragma unroll
    for (int j = 0; j < TNI; ++j) acc[i][j] = (floatx4){0.f, 0.f, 0.f, 0.f};

  for (int k0 = 0; k0 < E_; k0 += 32) {
    if (GATHER) {
      const float* A = (const float*)Av;
      #pragma unroll
      for (int i = 0; i < BM * 8 / 256; ++i) {   // BM x 8 float4 slots
        const int idx = tid + 256 * i;
        const int r = idx >> 3, c4 = idx & 7;
        const float4 v =
            *(const float4*)(A + (size_t)srow[r] * E_ + k0 + c4 * 4);
        half4 hv;
        hv.x = (_Float16)v.x; hv.y = (_Float16)v.y;
        hv.z = (_Float16)v.z; hv.w = (_Float16)v.w;
        *(half4*)&As[r][c4 * 4] = hv;
      }
    } else {
      const _Float16* A = (const _Float16*)Av;
      #pragma unroll
      for (int i = 0; i < BM * 4 / 256; ++i) {   // BM x 4 half8 slots
        const int idx = tid + 256 * i;
        const int r = idx >> 2, c = idx & 3;
        *(half8*)&As[r][c * 8] =
            *(const half8*)(A + (size_t)(m0 + r) * E_ + k0 + c * 8);
      }
    }
    #pragma unroll
    for (int i = 0; i < BN * 4 / 256; ++i) {
      const int idx = tid + 256 * i;
      const int r = idx >> 2, c = idx & 3;
      *(half8*)&Bs[r][c * 8] =
          *(const half8*)(W + (size_t)(n0 + r) * E_ + k0 + c * 8);
    }
    __syncthreads();

    half8 ah[TMI], bf[TNI];
    #pragma unroll
    for (int mi = 0; mi < TMI; ++mi)
      ah[mi] = *(const half8*)&As[wm0 + mi * 16 + ln15][kq * 8];
    #pragma unroll
    for (int ni = 0; ni < TNI; ++ni)
      bf[ni] = *(const half8*)&Bs[wn0 + ni * 16 + ln15][kq * 8];
    #pragma unroll
    for (int mi = 0; mi < TMI; ++mi)
      #pragma unroll
      for (int ni = 0; ni < TNI; ++ni)
        acc[mi][ni] = __builtin_amdgcn_mfma_f32_16x16x32_f16(
            ah[mi], bf[ni], acc[mi][ni], 0, 0, 0);
    __syncthreads();
  }

  float* __restrict__ Cf = args.Cf[blockIdx.z];
  _Float16* __restrict__ Ch = args.Ch[blockIdx.z];
  #pragma unroll
  for (int ni = 0; ni < TNI; ++ni) {
    const int col = n0 + wn0 + ni * 16 + ln15;
    const float bv = bias[col];
    #pragma unroll
    for (int mi = 0; mi < TMI; ++mi) {
      #pragma unroll
      for (int r = 0; r < 4; ++r) {
        const int m = m0 + wm0 + mi * 16 + kq * 4 + r;
        const int orow = SCATTER ? ((m & ~(T_ - 1)) + sidx[m]) : m;
        const float val = acc[mi][ni][r] + bv;
        if (FP16OUT) {
          Ch[(size_t)orow * E_ + col] = (_Float16)val;
        } else {
          Cf[(size_t)orow * E_ + col] = val;
        }
      }
    }
  }
}

// ---------------------------------------------------------------------------
// Kernel 4: local sliding-window attention — fp16 MFMA QK^T + slot-unified PV
// + fused depot-row scores (each block computes Q[dep].K[k] for its 16 keys,
// writing scg — replaces the old depot_scores kernel).
// ---------------------------------------------------------------------------
constexpr int QTm_ = 16;
constexpr int NSL_ = 80;
constexpr int VSP_ = 8;

__global__ __launch_bounds__(256) void attn_local_kernel(
    const _Float16* __restrict__ Qh, const _Float16* __restrict__ Kh,
    const _Float16* __restrict__ Vh, const float* __restrict__ c_s,
    const int* __restrict__ depot, _Float16* __restrict__ CTh,
    float* __restrict__ scg) {
  __shared__ float sc[QTm_][88];    // [query][slot]; slot 80 = depot
  __shared__ float cw[NSL_];
  __shared__ float cq[QTm_];
  __shared__ float kdep[HD_];
  __shared__ float qdep[HD_];

  const int tid = threadIdx.x;
  const int ntq = T_ / QTm_;                 // 64
  const int tq = blockIdx.x % ntq;
  const int bh = blockIdx.x / ntq;
  const int h = bh % H_, b = bh / H_;
  const int t0 = tq * QTm_;
  const int dep = depot[b];
  const int smin = min(max(t0 - 32, 0), T_ - WS_);
  const size_t baseBH = ((size_t)b * T_) * E_ + (size_t)h * HD_;

  if (tid < NSL_) {
    cw[tid] = c_s[b * T_ + min(smin + tid, T_ - 1)];
  } else if (tid < NSL_ + QTm_) {
    cq[tid - NSL_] = c_s[b * T_ + t0 + tid - NSL_];
  } else if (tid >= 128) {
    const int d = tid - 128;
    kdep[d] = (float)Kh[baseBH + (size_t)dep * E_ + d];
  }
  if (tid < HD_) qdep[tid] = (float)Qh[baseBH + (size_t)dep * E_ + tid];
  __syncthreads();

  const int wv = tid >> 6, lane = tid & 63;
  const int ln15 = lane & 15, kq = lane >> 4;

  // ---- MFMA scores: wave w covers key tiles {w} (+ tile 4 for wave 0) ----
  {
    const size_t qoff = baseBH + (size_t)(t0 + ln15) * E_ + kq * 8;
    half8 aH[4];
    #pragma unroll
    for (int ks = 0; ks < 4; ++ks)
      aH[ks] = *(const half8*)(Qh + qoff + ks * 32);
    for (int kt = wv; kt < 5; kt += 4) {
      const int key = min(smin + kt * 16 + ln15, T_ - 1);
      const size_t koff = baseBH + (size_t)key * E_ + kq * 8;
      floatx4 acc = (floatx4){0.f, 0.f, 0.f, 0.f};
      #pragma unroll
      for (int ks = 0; ks < 4; ++ks) {
        const half8 b8 = *(const half8*)(Kh + koff + ks * 32);
        acc = __builtin_amdgcn_mfma_f32_16x16x32_f16(aH[ks], b8, acc, 0, 0, 0);
      }
      #pragma unroll
      for (int r = 0; r < 4; ++r)
        sc[kq * 4 + r][kt * 16 + ln15] = acc[r];
    }
  }

  const float cdep = c_s[b * T_ + dep];

  // ---- depot column raw scores (vector dot; wave handles 4 queries) ----
  #pragma unroll
  for (int qi = 0; qi < 4; ++qi) {
    const int q = wv * 4 + qi;
    const int t = t0 + q;
    const size_t qo2 = baseBH + (size_t)t * E_;
    const float q1 = (float)Qh[qo2 + lane];
    const float q2 = (float)Qh[qo2 + 64 + lane];
    float part = fmaf(q1, kdep[lane], q2 * kdep[lane + 64]);
    #pragma unroll
    for (int o = 32; o > 0; o >>= 1) part += __shfl_xor(part, o);
    if (lane == 0) {
      const int st = min(max(t - 32, 0), T_ - WS_);
      const bool masked = (unsigned)(dep - st) < (unsigned)WS_;
      const float dd = cdep - cq[q];
      sc[q][80] = masked ? -3.0e38f
                         : part * SCALE_ - dd * dd * (1.0f / TAU_);
    }
  }

  // ---- fused depot-row scores: keys [t0, t0+16) vs Q[dep] -> scg ----
  #pragma unroll
  for (int qi = 0; qi < 4; ++qi) {
    const int k = t0 + wv * 4 + qi;
    const size_t ko = baseBH + (size_t)k * E_;
    const float k1 = (float)Kh[ko + lane];
    const float k2 = (float)Kh[ko + 64 + lane];
    float part = fmaf(qdep[lane], k1, qdep[lane + 64] * k2);
    #pragma unroll
    for (int o = 32; o > 0; o >>= 1) part += __shfl_xor(part, o);
    if (lane == 0) {
      const float dd = cw[k - smin] - cdep;
      scg[bh * T_ + k] = part * SCALE_ - dd * dd * (1.0f / TAU_);
    }
  }
  __syncthreads();

  // ---- softmax (wave handles 4 queries); invalid slots get weight 0 ----
  #pragma unroll
  for (int qi = 0; qi < 4; ++qi) {
    const int q = wv * 4 + qi;
    const int t = t0 + q;
    const int st = min(max(t - 32, 0), T_ - WS_);
    const int base = st - smin;            // 0..16
    const float cqv = cq[q];
    const int j1 = lane;
    float s1 = -3.0e38f;
    if (j1 >= base && j1 < base + WS_) {
      const float dd = cw[j1] - cqv;
      s1 = sc[q][j1] * SCALE_ - dd * dd * (1.0f / TAU_);
    }
    const int j2 = 64 + lane;
    float s2 = -3.0e38f;
    if (lane < 16 && j2 >= base && j2 < base + WS_) {
      const float dd = cw[j2] - cqv;
      s2 = sc[q][j2] * SCALE_ - dd * dd * (1.0f / TAU_);
    }
    const float sdep = sc[q][80];
    float m = fmaxf(s1, s2);
    #pragma unroll
    for (int o = 32; o > 0; o >>= 1) m = fmaxf(m, __shfl_xor(m, o));
    m = fmaxf(m, sdep);
    const float e1 = expf(s1 - m);
    const float e2 = (lane < 16) ? expf(s2 - m) : 0.f;
    float sum = e1 + e2;
    #pragma unroll
    for (int o = 32; o > 0; o >>= 1) sum += __shfl_xor(sum, o);
    const float edep = expf(sdep - m);
    sum += edep;
    const float inv = 1.0f / sum;
    sc[q][j1] = e1 * inv;
    if (lane < 16) sc[q][j2] = e2 * inv;
    if (lane == 0) sc[q][80] = edep * inv;
  }
  __syncthreads();

  // ---- PV: one pass over 81 slots; V loaded as half2 per (slot, lane) ----
  {
    const int dp = lane * 2;          // dims dp, dp+1
    float acc0[4], acc1[4];
    #pragma unroll
    for (int qi = 0; qi < 4; ++qi) { acc0[qi] = 0.f; acc1[qi] = 0.f; }
    for (int j = 0; j <= NSL_; ++j) {
      const int row = (j < NSL_) ? min(smin + j, T_ - 1) : dep;
      const half2v v = *(const half2v*)(Vh + baseBH + (size_t)row * E_ + dp);
      const float v1 = (float)v.x;
      const float v2 = (float)v.y;
      #pragma unroll
      for (int qi = 0; qi < 4; ++qi) {
        const float w = sc[wv * 4 + qi][j];
        acc0[qi] = fmaf(w, v1, acc0[qi]);
        acc1[qi] = fmaf(w, v2, acc1[qi]);
      }
    }
    #pragma unroll
    for (int qi = 0; qi < 4; ++qi) {
      const int t = t0 + wv * 4 + qi;
      half2v o;
      o.x = (_Float16)acc0[qi];
      o.y = (_Float16)acc1[qi];
      *(half2v*)(CTh + baseBH + (size_t)t * E_ + dp) = o;
    }
  }
}

// ---------------------------------------------------------------------------
// Kernel 5: depot ctx with fused softmax. 128 blocks (b,h,split); each block
// recomputes the (cheap) 1024-wide softmax from scg, then its 128-key split.
// ---------------------------------------------------------------------------
__global__ __launch_bounds__(256) void depot_ctx_kernel(
    const _Float16* __restrict__ Vh, const float* __restrict__ scg,
    float* __restrict__ part) {
  __shared__ float sc[T_];
  __shared__ float red[4];
  __shared__ float par[2][HD_];
  const int sp = blockIdx.x % VSP_;
  const int bh = blockIdx.x / VSP_;
  const int h = bh % H_, b = bh / H_;
  const int tid = threadIdx.x, wv = tid >> 6, lane = tid & 63;
  const float* s = scg + bh * T_;

  float lm = -3.0e38f;
  for (int k = tid; k < T_; k += 256) { sc[k] = s[k]; lm = fmaxf(lm, sc[k]); }
  #pragma unroll
  for (int o = 32; o > 0; o >>= 1) lm = fmaxf(lm, __shfl_xor(lm, o));
  if (lane == 0) red[wv] = lm;
  __syncthreads();
  const float M = fmaxf(fmaxf(red[0], red[1]), fmaxf(red[2], red[3]));
  __syncthreads();
  float ls = 0.f;
  float ev[T_ / 256];
  #pragma unroll
  for (int i = 0; i < T_ / 256; ++i) {
    ev[i] = expf(sc[tid + 256 * i] - M);
    ls += ev[i];
  }
  #pragma unroll
  for (int o = 32; o > 0; o >>= 1) ls += __shfl_xor(ls, o);
  if (lane == 0) red[wv] = ls;
  __syncthreads();
  const float inv = 1.0f / (red[0] + red[1] + red[2] + red[3]);
  #pragma unroll
  for (int i = 0; i < T_ / 256; ++i) sc[tid + 256 * i] = ev[i] * inv;
  __syncthreads();

  const int d = tid & 127, kg = tid >> 7;
  const size_t baseBH = ((size_t)b * T_) * E_ + (size_t)h * HD_;
  constexpr int KPB = T_ / VSP_;
  const int k0 = sp * KPB + kg * (KPB / 2);
  const _Float16* vbase = Vh + baseBH + d;
  float acc = 0.f;
  #pragma unroll 8
  for (int k = k0; k < k0 + KPB / 2; ++k) {
    acc = fmaf(sc[k], (float)vbase[(size_t)k * E_], acc);
  }
  par[kg][d] = acc;
  __syncthreads();
  if (tid < HD_) part[((size_t)sp * BB_ * H_ + bh) * HD_ + tid] =
      par[0][tid] + par[1][tid];
}

// ---------------------------------------------------------------------------
// Kernel 6: reduce depot splits, write depot ctx rows. 1 block.
// ---------------------------------------------------------------------------
__global__ __launch_bounds__(256) void depot_write_kernel(
    const float* __restrict__ part, const int* __restrict__ depot,
    _Float16* __restrict__ CTh) {
  for (int o = threadIdx.x; o < BB_ * H_ * HD_; o += 256) {
    const int bh = o >> 7, d = o & 127;
    float s = 0.f;
    #pragma unroll
    for (int sp = 0; sp < VSP_; ++sp)
      s += part[((size_t)sp * BB_ * H_ + bh) * HD_ + d];
    const int h = bh % H_, b = bh / H_;
    const int dep = depot[b];
    CTh[((size_t)b * T_ + dep) * E_ + (size_t)h * HD_ + d] = (_Float16)s;
  }
}

// ---------------------------------------------------------------------------
extern "C" void kernel_launch(void* const* d_in, const int* in_sizes, int n_in,
                              void* d_out, int out_size, void* d_ws, size_t ws_size,
                              hipStream_t stream) {
  const float* h     = (const float*)d_in[0];
  const float* coord = (const float*)d_in[1];
  const float* Wq    = (const float*)d_in[2];
  const float* Wqb   = (const float*)d_in[3];
  const float* Wk    = (const float*)d_in[4];
  const float* Wkb   = (const float*)d_in[5];
  const float* Wv    = (const float*)d_in[6];
  const float* Wvb   = (const float*)d_in[7];
  const float* Wo    = (const float*)d_in[8];
  const float* Wob   = (const float*)d_in[9];
  float* out = (float*)d_out;

  char* ws = (char*)d_ws;
  const size_t MATH_ = (size_t)BB_ * T_ * E_ * 2;  // 4 MB fp16
  const size_t WB   = (size_t)E_ * E_ * 2;         // 2 MB fp16
  size_t off = 0;
  _Float16* Qh  = (_Float16*)(ws + off); off += MATH_;
  _Float16* Kh  = (_Float16*)(ws + off); off += MATH_;
  _Float16* Vh  = (_Float16*)(ws + off); off += MATH_;
  _Float16* CTh = (_Float16*)(ws + off); off += MATH_;
  _Float16* Wh[4];
  for (int i = 0; i < 4; ++i) { Wh[i] = (_Float16*)(ws + off); off += WB; }
  float* c_s = (float*)(ws + off); off += (size_t)BB_ * T_ * 4;
  int* sidx  = (int*)(ws + off);   off += (size_t)BB_ * T_ * 4;
  int* depo  = (int*)(ws + off);   off += 256;
  float* scg  = (float*)(ws + off); off += (size_t)BB_ * H_ * T_ * 4;
  float* dpar = (float*)(ws + off); off += (size_t)VSP_ * BB_ * H_ * HD_ * 4;

  // 1. stable sort by coordinate (grid-parallel rank counting)
  sort_rank_kernel<<<BB_ * (T_ / STB_), 256, 0, stream>>>(coord, sidx, c_s, depo);

  // 2. weights -> fp16 single (1 launch, 4 matrices)
  WConv wc;
  wc.src[0] = Wq; wc.src[1] = Wk; wc.src[2] = Wv; wc.src[3] = Wo;
  for (int i = 0; i < 4; ++i) wc.dst[i] = Wh[i];
  convert_w_kernel<<<dim3(E_ * E_ / 1024, 1, 4), 256, 0, stream>>>(wc);

  // 3. QKV projections with fused gather+fp16-convert of h; fp16 out
  GemmArgs qa;
  qa.W[0] = Wh[0]; qa.W[1] = Wh[1]; qa.W[2] = Wh[2];
  qa.bias[0] = Wqb; qa.bias[1] = Wkb; qa.bias[2] = Wvb;
  qa.Cf[0] = qa.Cf[1] = qa.Cf[2] = nullptr;
  qa.Ch[0] = Qh; qa.Ch[1] = Kh; qa.Ch[2] = Vh;
  gemm_f16<128, 64, 1, 0, 1><<<dim3(E_ / 64, (BB_ * T_) / 128, 3), 256, 0, stream>>>(
      qa, h, sidx);

  // 4. sliding-window attention + fused depot-row scores
  attn_local_kernel<<<BB_ * H_ * (T_ / QTm_), 256, 0, stream>>>(
      Qh, Kh, Vh, c_s, depo, CTh, scg);

  // 5. depot ctx (fused softmax), then split-reduce + write
  depot_ctx_kernel<<<BB_ * H_ * VSP_, 256, 0, stream>>>(Vh, scg, dpar);
  depot_write_kernel<<<1, 256, 0, stream>>>(dpar, depo, CTh);

  // 6. output projection; fp32 out, fused un-sort scatter
  GemmArgs oa;
  oa.W[0] = oa.W[1] = oa.W[2] = Wh[3];
  oa.bias[0] = oa.bias[1] = oa.bias[2] = Wob;
  oa.Cf[0] = oa.Cf[1] = oa.Cf[2] = out;
  oa.Ch[0] = oa.Ch[1] = oa.Ch[2] = nullptr;
  gemm_f16<64, 64, 0, 1, 0><<<dim3(E_ / 64, (BB_ * T_) / 64, 1), 256, 0, stream>>>(
      oa, CTh, sidx);
}